// Round 14
// baseline (552.946 us; speedup 1.0000x reference)
//
#include <hip/hip_runtime.h>
#include <stdint.h>

// ---------------------------------------------------------------------------
// BGCGRU on MI355X. Round 14: extend r13's 2-blocks/CU retile to mid-chain:
//   - L2 P1/P2 -> kind2 <128,64> (512 blocks each).
//   - L3 three aggs -> kind2 (512 each).
//   - L9 three aggs + L11 + L13 -> kind3 <64,64> (512 each).
// All coverage invariants (nblk == gx * N/BN) hand-verified per TD.
// GEMM core and everything else byte-identical to r13.
// ---------------------------------------------------------------------------

typedef __bf16 bf16;
typedef float  f32x4  __attribute__((ext_vector_type(4)));
typedef __bf16 bf16x8 __attribute__((ext_vector_type(8)));
typedef __bf16 bf16x4v __attribute__((ext_vector_type(4)));

#define DEVI __device__ __forceinline__

DEVI void gload16(const bf16* g, bf16* l) {
  __builtin_amdgcn_global_load_lds(
      (const __attribute__((address_space(1))) void*)g,
      (__attribute__((address_space(3))) void*)l, 16, 0, 0);
}

struct GemmArgs {
  const bf16* A; const bf16* B;
  bf16* Cn;   // normal write:  [z] row-major [m][col], nullable
  bf16* Ct;   // transposed:    [z] row-major [col][m], nullable
  int lda, ldb, ldcn, ldct, K, zshB, zshC;
  long sB, sCn, sCt;   // per-z element strides
};

struct TaskDesc { GemmArgs g; int kind, gx, blk0, nblk; };
struct MultiArgs { TaskDesc t[3]; int nt; };

// 2-phase double-buffered NT GEMM, BK=64. 4 waves (2x2), 16x16x32 bf16 MFMA.
template<int BM, int BN>
DEVI void gemm_body(const GemmArgs& g, int bx, int by, bf16* smem) {
  constexpr int BK  = 64;
  constexpr int ASZ = BM * BK, BSZ = BN * BK;
  bf16* Abuf = smem;
  bf16* Bbuf = smem + 2 * ASZ;
  const int tid  = threadIdx.x;
  const int wave = tid >> 6;
  const int lane = tid & 63;
  const int wm = (wave >> 1) * (BM / 2);
  const int wn = (wave & 1) * (BN / 2);
  constexpr int FM = BM / 32;
  constexpr int FN = BN / 32;

  const int sseg = (((tid & 7) ^ ((tid >> 3) & 7))) * 8;  // swz source seg
  const int l15  = lane & 15;
  const int lq   = lane >> 4;

  const bf16* arow[BM / 32];
  #pragma unroll
  for (int c = 0; c < BM / 32; ++c)
    arow[c] = g.A + (long)(bx * BM + c * 32 + (tid >> 3)) * g.lda + sseg;
  const bf16* brow[BN / 32];
  const int maskB = (1 << g.zshB) - 1;
  #pragma unroll
  for (int c = 0; c < BN / 32; ++c) {
    const int nb = by * BN + c * 32 + (tid >> 3);
    brow[c] = g.B + (long)(nb >> g.zshB) * g.sB + (long)(nb & maskB) * g.ldb + sseg;
  }

  f32x4 acc[FM][FN] = {};

  auto stage = [&](int buf, int kt) {
    #pragma unroll
    for (int c = 0; c < BM / 32; ++c)
      gload16(arow[c] + kt, &Abuf[buf * ASZ + c * 2048 + tid * 8]);
    #pragma unroll
    for (int c = 0; c < BN / 32; ++c)
      gload16(brow[c] + kt, &Bbuf[buf * BSZ + c * 2048 + tid * 8]);
  };
  auto compute = [&](int cb) {
    #pragma unroll
    for (int kk = 0; kk < 2; ++kk) {
      bf16x8 af[FM], bfr[FN];
      #pragma unroll
      for (int i = 0; i < FM; ++i) {
        const int R = wm + i * 16 + l15;
        af[i] = *(const bf16x8*)
            &Abuf[cb * ASZ + R * 64 + ((kk * 4 + lq) ^ (l15 & 7)) * 8];
      }
      #pragma unroll
      for (int j = 0; j < FN; ++j) {
        const int R = wn + j * 16 + l15;
        bfr[j] = *(const bf16x8*)
            &Bbuf[cb * BSZ + R * 64 + ((kk * 4 + lq) ^ (l15 & 7)) * 8];
      }
      #pragma unroll
      for (int i = 0; i < FM; ++i)
        #pragma unroll
        for (int j = 0; j < FN; ++j)
          acc[i][j] = __builtin_amdgcn_mfma_f32_16x16x32_bf16(af[i], bfr[j],
                                                              acc[i][j], 0, 0, 0);
    }
  };

  const int nt = g.K / BK;
  stage(0, 0);
  __syncthreads();
  int cur = 0;
  for (int t = 0; t < nt; ++t) {
    if (t + 1 < nt) stage(cur ^ 1, (t + 1) * BK);
    compute(cur);
    __syncthreads();
    cur ^= 1;
  }

  const int gm0 = bx * BM + wm;
  const int gn0 = by * BN + wn;
  const int rowq = lq * 4;
  const int maskC = (1 << g.zshC) - 1;
  if (g.Cn) {
    #pragma unroll
    for (int i = 0; i < FM; ++i)
      #pragma unroll
      for (int j = 0; j < FN; ++j) {
        const int m0 = gm0 + i * 16 + rowq;
        const int ng = gn0 + j * 16 + l15;
        bf16* Cz = g.Cn + (long)(ng >> g.zshC) * g.sCn + (ng & maskC);
        #pragma unroll
        for (int r = 0; r < 4; ++r)
          Cz[(long)(m0 + r) * g.ldcn] = (bf16)acc[i][j][r];
      }
  }
  if (g.Ct) {
    #pragma unroll
    for (int i = 0; i < FM; ++i)
      #pragma unroll
      for (int j = 0; j < FN; ++j) {
        const int m0 = gm0 + i * 16 + rowq;
        const int ng = gn0 + j * 16 + l15;
        bf16x4v v = { (bf16)acc[i][j][0], (bf16)acc[i][j][1],
                      (bf16)acc[i][j][2], (bf16)acc[i][j][3] };
        *(bf16x4v*)(g.Ct + (long)(ng >> g.zshC) * g.sCt
                    + (long)(ng & maskC) * g.ldct + m0) = v;
      }
  }
}

__global__ __launch_bounds__(256) void gemm_multi(MultiArgs mu) {
  __shared__ bf16 smem[32768];    // 64 KB
  const int b = blockIdx.x;
  int ti = 0;
  if (mu.nt > 1 && b >= mu.t[1].blk0) ti = 1;
  if (mu.nt > 2 && b >= mu.t[2].blk0) ti = 2;
  const TaskDesc t = mu.t[ti];
  const int local = b - t.blk0;
  int bx, by;
  if ((t.gx & 7) == 0) {
    const int xcd = local & 7;
    const int idx = local >> 3;
    const int sub = t.gx >> 3;
    bx = xcd * sub + idx % sub;
    by = idx / sub;
  } else {
    bx = local % t.gx;
    by = local / t.gx;
  }
  if (t.kind == 0)      gemm_body<128, 128>(t.g, bx, by, smem);
  else if (t.kind == 1) gemm_body< 64, 128>(t.g, bx, by, smem);
  else if (t.kind == 2) gemm_body<128,  64>(t.g, bx, by, smem);
  else                  gemm_body< 64,  64>(t.g, bx, by, smem);
}

// ---------------- prep / elementwise kernels -------------------------------

struct PrepA {
  const float* src[6]; bf16* dst[6]; int fin[6], fout[6], sh[6], b0[7];
  const float* Wb1;  const float* E0_1; const float* E1_1;
  const float* Wbg2; const float* E0g2; const float* E1g2;
  bf16* We1T1; bf16* We1T2; float* T1f; float* T2f;
  const float* aw1; const float* al1; float* s1;
  const float* aw2; const float* al2; float* s2;
};

// prep_all1: [0,16384) pads; [16384,20480) S1 transpose; [20480,21073) prep_a;
//            [21073,23121) tem1 build.
struct Prep1Args {
  const float* S0; const float* S1; const float* M;
  bf16* S0b; bf16* S1b; bf16* Mb; bf16* S1Tb;
  const float* x; const float* h; bf16* tem;
  PrepA pa;
};
__global__ __launch_bounds__(256) void prep_all1(Prep1Args g) {
  __shared__ float tt[64][65];
  const int b = blockIdx.x, t = threadIdx.x;
  if (b < 16384) {
    const int y = b >> 1;
    const int c0 = ((b & 1) * 256 + t) * 8;
    const float* in; bf16* out; int R, C, Cp, r;
    if (y < 2048)      { in = g.S0; out = g.S0b; R = 2000; C = 2000; Cp = 2048; r = y; }
    else if (y < 6144) { in = g.S1; out = g.S1b; R = 4000; C = 4000; Cp = 4096; r = y - 2048; }
    else               { in = g.M;  out = g.Mb;  R = 2000; C = 4000; Cp = 4096; r = y - 6144; }
    if (c0 >= Cp) return;
    bf16x8 v;
    if (r < R && c0 + 7 < C) {
      const float4 a = *(const float4*)&in[(long)r * C + c0];
      const float4 bb = *(const float4*)&in[(long)r * C + c0 + 4];
      v[0]=(bf16)a.x; v[1]=(bf16)a.y; v[2]=(bf16)a.z; v[3]=(bf16)a.w;
      v[4]=(bf16)bb.x; v[5]=(bf16)bb.y; v[6]=(bf16)bb.z; v[7]=(bf16)bb.w;
    } else {
      #pragma unroll
      for (int k = 0; k < 8; ++k) {
        const int c = c0 + k;
        v[k] = (bf16)((r < R && c < C) ? in[(long)r * C + c] : 0.f);
      }
    }
    *(bf16x8*)&out[(long)r * Cp + c0] = v;
  } else if (b < 20480) {
    const int tb = b - 16384;
    const int r0 = (tb & 63) * 64;
    const int c0 = (tb >> 6) * 64;
    const int row = t >> 2;
    const int seg = (t & 3) * 16;
    const int r = r0 + row;
    #pragma unroll
    for (int q = 0; q < 4; ++q) {
      const int c = c0 + seg + q * 4;
      float4 a;
      if (r < 4000 && c + 3 < 4000) a = *(const float4*)&g.S1[(long)r * 4000 + c];
      else {
        a.x = (r < 4000 && c     < 4000) ? g.S1[(long)r * 4000 + c    ] : 0.f;
        a.y = (r < 4000 && c + 1 < 4000) ? g.S1[(long)r * 4000 + c + 1] : 0.f;
        a.z = (r < 4000 && c + 2 < 4000) ? g.S1[(long)r * 4000 + c + 2] : 0.f;
        a.w = (r < 4000 && c + 3 < 4000) ? g.S1[(long)r * 4000 + c + 3] : 0.f;
      }
      tt[seg + q * 4 + 0][row] = a.x;
      tt[seg + q * 4 + 1][row] = a.y;
      tt[seg + q * 4 + 2][row] = a.z;
      tt[seg + q * 4 + 3][row] = a.w;
    }
    __syncthreads();
    const int orow = t >> 2;
    const int oseg = (t & 3) * 16;
    bf16x8 v0, v1;
    #pragma unroll
    for (int k = 0; k < 8; ++k) {
      v0[k] = (bf16)tt[orow][oseg + k];
      v1[k] = (bf16)tt[orow][oseg + 8 + k];
    }
    *(bf16x8*)&g.S1Tb[(long)(c0 + orow) * 4096 + r0 + oseg] = v0;
    *(bf16x8*)&g.S1Tb[(long)(c0 + orow) * 4096 + r0 + oseg + 8] = v1;
  } else if (b < 21073) {
    const PrepA& a = g.pa;
    const int pb = b - 20480;
    if (pb < 416) {
      int k = 0;
      while (pb >= a.b0[k + 1]) ++k;
      const int i = (pb - a.b0[k]) * 256 + t;
      const int c = i >> a.sh[k], f = i & ((1 << a.sh[k]) - 1);
      float v = (f < a.fin[k]) ? a.src[k][(long)f * a.fout[k] + c] : 0.f;
      a.dst[k][i] = (bf16)v;
    } else if (pb < 480) {
      const int i = (pb - 416) * 256 + t;
      const int c = i >> 7, f = i & 127;
      float s = 0.f;
      if (f < 66) {
        #pragma unroll 16
        for (int k = 0; k < 128; ++k) s += a.E0_1[k * 128 + c] * a.Wb1[f * 128 + k];
      }
      a.We1T1[c * 128 + f] = (bf16)s;
    } else if (pb < 512) {
      const int i = (pb - 480) * 256 + t;
      const int c = i >> 7, f = i & 127;
      float s = 0.f;
      if (f < 66) {
        #pragma unroll 16
        for (int k = 0; k < 64; ++k) s += a.E0g2[k * 64 + c] * a.Wbg2[f * 64 + k];
      }
      a.We1T2[c * 128 + f] = (bf16)s;
    } else if (pb < 576) {
      const int i = (pb - 512) * 256 + t;
      const int j = i >> 7, c = i & 127;
      float s = 0.f;
      #pragma unroll 16
      for (int k = 0; k < 128; ++k) s += a.E0_1[j * 128 + k] * a.E1_1[k * 128 + c];
      a.T1f[j * 128 + c] = s;
    } else if (pb < 592) {
      const int i = (pb - 576) * 256 + t;
      const int j = i >> 6, c = i & 63;
      float s = 0.f;
      #pragma unroll 16
      for (int k = 0; k < 64; ++k) s += a.E0g2[j * 64 + k] * a.E1g2[k * 64 + c];
      a.T2f[j * 64 + c] = s;
    } else {
      if (t < 128) {
        float s = 0.f;
        for (int w = 0; w < 128; ++w) s += a.aw1[w * 128 + t] * a.al1[w];
        a.s1[t] = s;
      } else if (t < 192) {
        const int f = t - 128;
        float s = 0.f;
        for (int w = 0; w < 64; ++w) s += a.aw2[w * 64 + f] * a.al2[w];
        a.s2[f] = s;
      }
    }
  } else {
    const long base = (long)(b - 21073) * 2048 + t * 8;
    const int gn = (int)(base >> 7);
    const int f0 = (int)(base & 127);
    const int z = gn >> 11, n = gn & 2047;
    bf16x8 v;
    #pragma unroll
    for (int k = 0; k < 8; ++k) {
      const int f = f0 + k;
      float val = 0.f;
      if (n < 2000) {
        if (f < 2)       val = g.x[(long)z * 4000 + n * 2 + f];
        else if (f < 66) val = g.h[(long)z * 128000 + (long)n * 64 + (f - 2)];
      }
      v[k] = (bf16)val;
    }
    *(bf16x8*)&g.tem[base] = v;
  }
}

// prep_all2: We2^T = Wb*T (96 blocks).
struct Prep2Args {
  const float* Wb1; const float* Wbg2;
  const float* T1f; const float* T2f;
  bf16* We2T1; bf16* We2T2;
};
__global__ __launch_bounds__(256) void prep_all2(Prep2Args a) {
  const int b = blockIdx.x, t = threadIdx.x;
  if (b < 64) {
    const int i = b * 256 + t;
    const int c = i >> 7, f = i & 127;
    float s = 0.f;
    if (f < 66) {
      #pragma unroll 16
      for (int j = 0; j < 128; ++j) s += a.Wb1[f * 128 + j] * a.T1f[j * 128 + c];
    }
    a.We2T1[c * 128 + f] = (bf16)s;
  } else {
    const int i = (b - 64) * 256 + t;
    const int c = i >> 7, f = i & 127;
    float s = 0.f;
    if (f < 66) {
      #pragma unroll 16
      for (int j = 0; j < 64; ++j) s += a.Wbg2[f * 64 + j] * a.T2f[j * 64 + c];
    }
    a.We2T2[c * 128 + f] = (bf16)s;
  }
}

// g1 attention (F=128) fused with build_tem2.
__global__ void attention_fuse(const bf16* hop0, const bf16* hop1,
                               const bf16* hop2, const float* s,
                               const float* x, const float* h,
                               bf16* fea64, bf16* tem) {
  const int nloc = blockIdx.x * 4 + (threadIdx.x >> 6);
  const int b = blockIdx.y;
  const int lane = threadIdx.x & 63;
  const long bn = (long)b * 2048 + nloc;
  float h0[2], h1[2], h2[2];
  float d0 = 0.f, d1 = 0.f, d2 = 0.f;
  #pragma unroll
  for (int q = 0; q < 2; ++q) {
    const int f = lane + q * 64;
    h0[q] = (float)hop0[bn * 256 + f];
    h1[q] = (float)hop1[bn * 256 + f];
    h2[q] = (float)hop2[bn * 128 + f];
    const float sv = s[f];
    d0 += h0[q] * sv; d1 += h1[q] * sv; d2 += h2[q] * sv;
  }
  #pragma unroll
  for (int o = 32; o; o >>= 1) {
    d0 += __shfl_xor(d0, o); d1 += __shfl_xor(d1, o); d2 += __shfl_xor(d2, o);
  }
  const float mx = fmaxf(d0, fmaxf(d1, d2));
  float e0 = expf(d0 - mx), e1 = expf(d1 - mx), e2 = expf(d2 - mx);
  const float inv = 1.f / (e0 + e1 + e2);
  e0 *= inv; e1 *= inv; e2 *= inv;
  const float o0 = e0 * h0[0] + e1 * h1[0] + e2 * h2[0];
  const float o1 = e0 * h0[1] + e1 * h1[1] + e2 * h2[1];   // r-gate
  fea64[bn * 64 + lane] = (bf16)o0;
  const float r0 = __shfl(o1, (lane >= 2) ? lane - 2 : 0);
  const float r1 = __shfl(o1, (62 + lane) & 63);
  float t0 = 0.f, t1 = 0.f;
  if (nloc < 2000) {
    const long hb = (long)b * 128000 + (long)nloc * 64;
    if (lane < 2) {
      t0 = x[(long)b * 4000 + nloc * 2 + lane];
      t1 = (1.f / (1.f + expf(-r1))) * h[hb + 62 + lane];
    } else {
      t0 = (1.f / (1.f + expf(-r0))) * h[hb + (lane - 2)];
    }
  }
  tem[bn * 128 + lane] = (bf16)t0;
  tem[bn * 128 + 64 + lane] = (bf16)t1;
}

// g2 attention (F=64) fused with gru_out.
__global__ void attention_gru(const bf16* hop0, const bf16* hop1,
                              const bf16* hop2, const float* s,
                              const bf16* fea64, const float* h, float* out) {
  const int nloc = blockIdx.x * 4 + (threadIdx.x >> 6);
  const int b = blockIdx.y;
  const int lane = threadIdx.x & 63;
  const long bn = (long)b * 2048 + nloc;
  const float a0 = (float)hop0[bn * 128 + lane];
  const float a1 = (float)hop1[bn * 128 + lane];
  const float a2 = (float)hop2[bn * 64 + lane];
  const float sv = s[lane];
  float d0 = a0 * sv, d1 = a1 * sv, d2 = a2 * sv;
  #pragma unroll
  for (int o = 32; o; o >>= 1) {
    d0 += __shfl_xor(d0, o); d1 += __shfl_xor(d1, o); d2 += __shfl_xor(d2, o);
  }
  const float mx = fmaxf(d0, fmaxf(d1, d2));
  float e0 = expf(d0 - mx), e1 = expf(d1 - mx), e2 = expf(d2 - mx);
  const float inv = 1.f / (e0 + e1 + e2);
  e0 *= inv; e1 *= inv; e2 *= inv;
  const float c = e0 * a0 + e1 * a1 + e2 * a2;
  if (nloc < 2000) {
    const float z  = (float)fea64[bn * 64 + lane];
    const float hv = h[(long)b * 128000 + (long)nloc * 64 + lane];
    const float zs = 1.f / (1.f + expf(-z));
    out[(long)b * 128000 + (long)nloc * 64 + lane] =
        zs * hv + (1.f - zs) * tanhf(c);
  }
}

__global__ void ws_diag(float* out, int n, float v) {
  int i = blockIdx.x * blockDim.x + threadIdx.x;
  if (i < n) out[i] = v;
}

// ---------------------------------------------------------------------------

static TaskDesc TD(int kind, int gx, int nblk,
                   const bf16* A, int lda,
                   const bf16* B, int ldb, int zshB, long sB,
                   bf16* Cn, int ldcn, long sCn,
                   bf16* Ct, int ldct, long sCt, int zshC, int K) {
  TaskDesc t;
  t.g = GemmArgs{A, B, Cn, Ct, lda, ldb, ldcn, ldct, K, zshB, zshC, sB, sCn, sCt};
  t.kind = kind; t.gx = gx; t.blk0 = 0; t.nblk = nblk;
  return t;
}
static void runT(hipStream_t st, int n, const TaskDesc* ts) {
  MultiArgs m = {};
  int off = 0;
  for (int i = 0; i < n; ++i) { m.t[i] = ts[i]; m.t[i].blk0 = off; off += ts[i].nblk; }
  m.nt = n;
  gemm_multi<<<off, 256, 0, st>>>(m);
}
static void run1(hipStream_t st, TaskDesc a) { runT(st, 1, &a); }
static void run2p(hipStream_t st, TaskDesc a, TaskDesc b) {
  TaskDesc ts[2] = {a, b}; runT(st, 2, ts);
}
static void run3p(hipStream_t st, TaskDesc a, TaskDesc b, TaskDesc c) {
  TaskDesc ts[3] = {a, b, c}; runT(st, 3, ts);
}

extern "C" void kernel_launch(void* const* d_in, const int* in_sizes, int n_in,
                              void* d_out, int out_size, void* d_ws, size_t ws_size,
                              hipStream_t stream) {
  const float* x    = (const float*)d_in[0];
  const float* hid  = (const float*)d_in[1];
  const float* S0   = (const float*)d_in[2];
  const float* S1   = (const float*)d_in[3];
  const float* M    = (const float*)d_in[4];

  char* base = (char*)d_ws;
  size_t off = 0;
  auto alloc = [&](size_t bytes) -> void* {
    void* r = base + off;
    off += (bytes + 255) & ~(size_t)255;
    return r;
  };

  bf16* S0b  = (bf16*)alloc(2048ull * 2048 * 2);   //  8 MB
  bf16* S1b  = (bf16*)alloc(4096ull * 4096 * 2);   // 32 MB
  bf16* S1Tb = (bf16*)alloc(4096ull * 4096 * 2);   // 32 MB
  bf16* Mb   = (bf16*)alloc(2048ull * 4096 * 2);   // 16 MB
  bf16* tem  = (bf16*)alloc(16ull * 2048 * 128 * 2);  // 8 MB

  bf16* WtAll1 = (bf16*)alloc(384 * 128 * 2);
  bf16* W1T    = (bf16*)alloc(128 * 256 * 2);
  bf16* W2T    = (bf16*)alloc(128 * 256 * 2);
  bf16* WtAll2 = (bf16*)alloc(192 * 128 * 2);
  bf16* W1g2T  = (bf16*)alloc(64 * 128 * 2);
  bf16* W2g2T  = (bf16*)alloc(64 * 128 * 2);
  float* s1  = (float*)alloc(128 * 4);
  float* s2  = (float*)alloc(64 * 4);
  float* T1f = (float*)alloc(128 * 128 * 4);
  float* T2f = (float*)alloc(64 * 64 * 4);

  bf16* P1 = (bf16*)alloc(2048ull * 2048 * 2);     //  8 MB
  bf16* P2 = (bf16*)alloc(2048ull * 2048 * 2);     //  8 MB
  bf16* R  = (bf16*)alloc(2048ull * 4096 * 2);     // 16 MB
  bf16* R2 = (bf16*)alloc(2048ull * 4096 * 2);     // 16 MB

  if (off > ws_size) {
    ws_diag<<<4, 256, 0, stream>>>((float*)d_out, 1024, (float)(ws_size >> 20));
    return;
  }

  // Overlays (liveness-audited, identical to r8..r13):
  bf16* xAll   = S1b;
  bf16* cat1   = S1Tb;
  bf16* cat2   = (bf16*)((char*)S1Tb + 16777216);
  bf16* cpb    = S1b;
  bf16* hop2   = (bf16*)((char*)S1b + 8388608);
  bf16* fea64  = (bf16*)((char*)S1b + 16777216);
  bf16* xAll2  = R;
  bf16* cat1_2 = S1Tb;
  bf16* cat2_2 = (bf16*)((char*)S1Tb + 8388608);
  bf16* cpb2   = S1b;
  bf16* hop2_2 = (bf16*)((char*)S1b + 8388608);

  // ---- prep (2 launches) ----
  Prep1Args p1;
  p1.S0 = S0; p1.S1 = S1; p1.M = M;
  p1.S0b = S0b; p1.S1b = S1b; p1.Mb = Mb; p1.S1Tb = S1Tb;
  p1.x = x; p1.h = hid; p1.tem = tem;
  {
    PrepA& pa = p1.pa;
    const float* wsrc[6] = {(const float*)d_in[6], (const float*)d_in[7],
                            (const float*)d_in[8], (const float*)d_in[14],
                            (const float*)d_in[15], (const float*)d_in[16]};
    bf16* wdst[6] = {WtAll1, W1T, W2T, WtAll2, W1g2T, W2g2T};
    static const int wfin[6]  = {66, 256, 256, 66, 128, 128};
    static const int wfout[6] = {128, 128, 128, 64, 64, 64};
    static const int wsh[6]   = {7, 8, 8, 7, 7, 7};
    static const int wb0[7]   = {0, 64, 192, 320, 352, 384, 416};
    for (int i = 0; i < 6; ++i) {
      pa.src[i] = wsrc[i]; pa.dst[i] = wdst[i];
      pa.fin[i] = wfin[i]; pa.fout[i] = wfout[i]; pa.sh[i] = wsh[i];
    }
    for (int i = 0; i < 7; ++i) pa.b0[i] = wb0[i];
    pa.Wb1  = (const float*)d_in[5];  pa.E0_1 = (const float*)d_in[9];
    pa.E1_1 = (const float*)d_in[10];
    pa.Wbg2 = (const float*)d_in[13]; pa.E0g2 = (const float*)d_in[17];
    pa.E1g2 = (const float*)d_in[18];
    pa.We1T1 = WtAll1 + 128 * 128;  pa.We1T2 = WtAll2 + 64 * 128;
    pa.T1f = T1f; pa.T2f = T2f;
    pa.aw1 = (const float*)d_in[11]; pa.al1 = (const float*)d_in[12]; pa.s1 = s1;
    pa.aw2 = (const float*)d_in[19]; pa.al2 = (const float*)d_in[20]; pa.s2 = s2;
  }
  prep_all1<<<23121, 256, 0, stream>>>(p1);
  Prep2Args p2{(const float*)d_in[5], (const float*)d_in[13], T1f, T2f,
               WtAll1 + 256 * 128, WtAll2 + 128 * 128};
  prep_all2<<<96, 256, 0, stream>>>(p2);

  // ---- L1: R = M*S1, R2 = M*S1^T (kind0, 4 blocks/CU) ----
  run2p(stream,
    TD(0, 16, 512, Mb,4096, S1Tb,4096,12,0, R,4096,0,  nullptr,0,0, 12, 4096),
    TD(0, 16, 512, Mb,4096, S1b,4096,12,0,  R2,4096,0, nullptr,0,0, 12, 4096));
  // ---- L2: P1 = R*M^T, P2 = R*R2^T (kind2, 512 each), xAll proj ----
  run3p(stream,
    TD(2, 16, 512, R,4096, Mb,4096,11,0, P1,2048,0, nullptr,0,0, 11, 4096),
    TD(2, 16, 512, R,4096, R2,4096,11,0, P2,2048,0, nullptr,0,0, 11, 4096),
    TD(0, 3, 768, WtAll1,128, tem,128,11,2048L*128,
       xAll,2048,384L*2048, nullptr,0,0, 11, 128));
  // ---- L3: cat1 = [S0*xW0 | P1*xe1], cat2_hi = P2*xe2 (kind2, 512 each) ----
  run3p(stream,
    TD(2, 16, 512, S0b,2048, xAll,2048,7,384L*2048,
       cat1,256,2048L*256, nullptr,0,0, 7, 2048),
    TD(2, 16, 512, P1,2048, xAll+128*2048,2048,7,384L*2048,
       cat1+128,256,2048L*256, nullptr,0,0, 7, 2048),
    TD(2, 16, 512, P2,2048, xAll+256*2048,2048,7,384L*2048,
       cat2+128,256,2048L*256, nullptr,0,0, 7, 2048));
  // ---- L4-L7: serial g1 tail (r13 form, 512-block) ----
  run1(stream, TD(2, 1, 512, W1T,256, cat1,256,11,2048L*256,
                  cpb,2048,128L*2048, nullptr,0,0, 11, 256));
  run1(stream, TD(2, 16, 512, S0b,2048, cpb,2048,7,128L*2048,
                  cat2,256,2048L*256, nullptr,0,0, 7, 2048));
  run1(stream, TD(2, 1, 512, W2T,256, cat2,256,11,2048L*256,
                  cpb,2048,128L*2048, nullptr,0,0, 11, 256));
  run1(stream, TD(2, 16, 512, S0b,2048, cpb,2048,7,128L*2048,
                  hop2,128,2048L*128, nullptr,0,0, 7, 2048));
  attention_fuse<<<dim3(512, 16), 256, 0, stream>>>(cat1, cat2, hop2, s1,
                                                    x, hid, fea64, tem);

  // ---- L8: g2 projection ----
  run1(stream, TD(1, 3, 768, WtAll2,128, tem,128,11,2048L*128,
                  xAll2,2048,192L*2048, nullptr,0,0, 11, 128));
  // ---- L9: g2 leading aggs (kind3 <64,64>, 512 each) ----
  run3p(stream,
    TD(3, 32, 512, S0b,2048, xAll2,2048,6,192L*2048,
       cat1_2,128,2048L*128, nullptr,0,0, 6, 2048),
    TD(3, 32, 512, P1,2048, xAll2+64*2048,2048,6,192L*2048,
       cat1_2+64,128,2048L*128, nullptr,0,0, 6, 2048),
    TD(3, 32, 512, P2,2048, xAll2+128*2048,2048,6,192L*2048,
       cat2_2+64,128,2048L*128, nullptr,0,0, 6, 2048));
  // ---- L10-L13: serial g2 tail (L11/L13 kind3 512) ----
  run1(stream, TD(3, 1, 512, W1g2T,128, cat1_2,128,11,2048L*128,
                  cpb2,2048,64L*2048, nullptr,0,0, 11, 128));
  run1(stream, TD(3, 32, 512, S0b,2048, cpb2,2048,6,64L*2048,
                  cat2_2,128,2048L*128, nullptr,0,0, 6, 2048));
  run1(stream, TD(3, 1, 512, W2g2T,128, cat2_2,128,11,2048L*128,
                  cpb2,2048,64L*2048, nullptr,0,0, 11, 128));
  run1(stream, TD(3, 32, 512, S0b,2048, cpb2,2048,6,64L*2048,
                  hop2_2,64,2048L*64, nullptr,0,0, 6, 2048));
  attention_gru<<<dim3(512, 16), 256, 0, stream>>>(cat1_2, cat2_2, hop2_2, s2,
                                                   fea64, hid, (float*)d_out);
}

// Round 15
// 509.912 us; speedup vs baseline: 1.0844x; 1.0844x over previous
//
#include <hip/hip_runtime.h>
#include <stdint.h>

// ---------------------------------------------------------------------------
// BGCGRU on MI355X. Round 15: revert r14's mid-chain retile (it added staging
// traffic on launches that were ALREADY 2-blocks/CU co-resident); keep r13's
// schedule exactly, except L11/L13 (the only remaining 1-block/CU dispatches)
// -> kind3 <64,64> 512-block form (correctness-validated in r14).
// ---------------------------------------------------------------------------

typedef __bf16 bf16;
typedef float  f32x4  __attribute__((ext_vector_type(4)));
typedef __bf16 bf16x8 __attribute__((ext_vector_type(8)));
typedef __bf16 bf16x4v __attribute__((ext_vector_type(4)));

#define DEVI __device__ __forceinline__

DEVI void gload16(const bf16* g, bf16* l) {
  __builtin_amdgcn_global_load_lds(
      (const __attribute__((address_space(1))) void*)g,
      (__attribute__((address_space(3))) void*)l, 16, 0, 0);
}

struct GemmArgs {
  const bf16* A; const bf16* B;
  bf16* Cn;   // normal write:  [z] row-major [m][col], nullable
  bf16* Ct;   // transposed:    [z] row-major [col][m], nullable
  int lda, ldb, ldcn, ldct, K, zshB, zshC;
  long sB, sCn, sCt;   // per-z element strides
};

struct TaskDesc { GemmArgs g; int kind, gx, blk0, nblk; };
struct MultiArgs { TaskDesc t[3]; int nt; };

// 2-phase double-buffered NT GEMM, BK=64. 4 waves (2x2), 16x16x32 bf16 MFMA.
template<int BM, int BN>
DEVI void gemm_body(const GemmArgs& g, int bx, int by, bf16* smem) {
  constexpr int BK  = 64;
  constexpr int ASZ = BM * BK, BSZ = BN * BK;
  bf16* Abuf = smem;
  bf16* Bbuf = smem + 2 * ASZ;
  const int tid  = threadIdx.x;
  const int wave = tid >> 6;
  const int lane = tid & 63;
  const int wm = (wave >> 1) * (BM / 2);
  const int wn = (wave & 1) * (BN / 2);
  constexpr int FM = BM / 32;
  constexpr int FN = BN / 32;

  const int sseg = (((tid & 7) ^ ((tid >> 3) & 7))) * 8;  // swz source seg
  const int l15  = lane & 15;
  const int lq   = lane >> 4;

  const bf16* arow[BM / 32];
  #pragma unroll
  for (int c = 0; c < BM / 32; ++c)
    arow[c] = g.A + (long)(bx * BM + c * 32 + (tid >> 3)) * g.lda + sseg;
  const bf16* brow[BN / 32];
  const int maskB = (1 << g.zshB) - 1;
  #pragma unroll
  for (int c = 0; c < BN / 32; ++c) {
    const int nb = by * BN + c * 32 + (tid >> 3);
    brow[c] = g.B + (long)(nb >> g.zshB) * g.sB + (long)(nb & maskB) * g.ldb + sseg;
  }

  f32x4 acc[FM][FN] = {};

  auto stage = [&](int buf, int kt) {
    #pragma unroll
    for (int c = 0; c < BM / 32; ++c)
      gload16(arow[c] + kt, &Abuf[buf * ASZ + c * 2048 + tid * 8]);
    #pragma unroll
    for (int c = 0; c < BN / 32; ++c)
      gload16(brow[c] + kt, &Bbuf[buf * BSZ + c * 2048 + tid * 8]);
  };
  auto compute = [&](int cb) {
    #pragma unroll
    for (int kk = 0; kk < 2; ++kk) {
      bf16x8 af[FM], bfr[FN];
      #pragma unroll
      for (int i = 0; i < FM; ++i) {
        const int R = wm + i * 16 + l15;
        af[i] = *(const bf16x8*)
            &Abuf[cb * ASZ + R * 64 + ((kk * 4 + lq) ^ (l15 & 7)) * 8];
      }
      #pragma unroll
      for (int j = 0; j < FN; ++j) {
        const int R = wn + j * 16 + l15;
        bfr[j] = *(const bf16x8*)
            &Bbuf[cb * BSZ + R * 64 + ((kk * 4 + lq) ^ (l15 & 7)) * 8];
      }
      #pragma unroll
      for (int i = 0; i < FM; ++i)
        #pragma unroll
        for (int j = 0; j < FN; ++j)
          acc[i][j] = __builtin_amdgcn_mfma_f32_16x16x32_bf16(af[i], bfr[j],
                                                              acc[i][j], 0, 0, 0);
    }
  };

  const int nt = g.K / BK;
  stage(0, 0);
  __syncthreads();
  int cur = 0;
  for (int t = 0; t < nt; ++t) {
    if (t + 1 < nt) stage(cur ^ 1, (t + 1) * BK);
    compute(cur);
    __syncthreads();
    cur ^= 1;
  }

  const int gm0 = bx * BM + wm;
  const int gn0 = by * BN + wn;
  const int rowq = lq * 4;
  const int maskC = (1 << g.zshC) - 1;
  if (g.Cn) {
    #pragma unroll
    for (int i = 0; i < FM; ++i)
      #pragma unroll
      for (int j = 0; j < FN; ++j) {
        const int m0 = gm0 + i * 16 + rowq;
        const int ng = gn0 + j * 16 + l15;
        bf16* Cz = g.Cn + (long)(ng >> g.zshC) * g.sCn + (ng & maskC);
        #pragma unroll
        for (int r = 0; r < 4; ++r)
          Cz[(long)(m0 + r) * g.ldcn] = (bf16)acc[i][j][r];
      }
  }
  if (g.Ct) {
    #pragma unroll
    for (int i = 0; i < FM; ++i)
      #pragma unroll
      for (int j = 0; j < FN; ++j) {
        const int m0 = gm0 + i * 16 + rowq;
        const int ng = gn0 + j * 16 + l15;
        bf16x4v v = { (bf16)acc[i][j][0], (bf16)acc[i][j][1],
                      (bf16)acc[i][j][2], (bf16)acc[i][j][3] };
        *(bf16x4v*)(g.Ct + (long)(ng >> g.zshC) * g.sCt
                    + (long)(ng & maskC) * g.ldct + m0) = v;
      }
  }
}

__global__ __launch_bounds__(256) void gemm_multi(MultiArgs mu) {
  __shared__ bf16 smem[32768];    // 64 KB
  const int b = blockIdx.x;
  int ti = 0;
  if (mu.nt > 1 && b >= mu.t[1].blk0) ti = 1;
  if (mu.nt > 2 && b >= mu.t[2].blk0) ti = 2;
  const TaskDesc t = mu.t[ti];
  const int local = b - t.blk0;
  int bx, by;
  if ((t.gx & 7) == 0) {
    const int xcd = local & 7;
    const int idx = local >> 3;
    const int sub = t.gx >> 3;
    bx = xcd * sub + idx % sub;
    by = idx / sub;
  } else {
    bx = local % t.gx;
    by = local / t.gx;
  }
  if (t.kind == 0)      gemm_body<128, 128>(t.g, bx, by, smem);
  else if (t.kind == 1) gemm_body< 64, 128>(t.g, bx, by, smem);
  else if (t.kind == 2) gemm_body<128,  64>(t.g, bx, by, smem);
  else                  gemm_body< 64,  64>(t.g, bx, by, smem);
}

// ---------------- prep / elementwise kernels -------------------------------

struct PrepA {
  const float* src[6]; bf16* dst[6]; int fin[6], fout[6], sh[6], b0[7];
  const float* Wb1;  const float* E0_1; const float* E1_1;
  const float* Wbg2; const float* E0g2; const float* E1g2;
  bf16* We1T1; bf16* We1T2; float* T1f; float* T2f;
  const float* aw1; const float* al1; float* s1;
  const float* aw2; const float* al2; float* s2;
};

// prep_all1: [0,16384) pads; [16384,20480) S1 transpose; [20480,21073) prep_a;
//            [21073,23121) tem1 build.
struct Prep1Args {
  const float* S0; const float* S1; const float* M;
  bf16* S0b; bf16* S1b; bf16* Mb; bf16* S1Tb;
  const float* x; const float* h; bf16* tem;
  PrepA pa;
};
__global__ __launch_bounds__(256) void prep_all1(Prep1Args g) {
  __shared__ float tt[64][65];
  const int b = blockIdx.x, t = threadIdx.x;
  if (b < 16384) {
    const int y = b >> 1;
    const int c0 = ((b & 1) * 256 + t) * 8;
    const float* in; bf16* out; int R, C, Cp, r;
    if (y < 2048)      { in = g.S0; out = g.S0b; R = 2000; C = 2000; Cp = 2048; r = y; }
    else if (y < 6144) { in = g.S1; out = g.S1b; R = 4000; C = 4000; Cp = 4096; r = y - 2048; }
    else               { in = g.M;  out = g.Mb;  R = 2000; C = 4000; Cp = 4096; r = y - 6144; }
    if (c0 >= Cp) return;
    bf16x8 v;
    if (r < R && c0 + 7 < C) {
      const float4 a = *(const float4*)&in[(long)r * C + c0];
      const float4 bb = *(const float4*)&in[(long)r * C + c0 + 4];
      v[0]=(bf16)a.x; v[1]=(bf16)a.y; v[2]=(bf16)a.z; v[3]=(bf16)a.w;
      v[4]=(bf16)bb.x; v[5]=(bf16)bb.y; v[6]=(bf16)bb.z; v[7]=(bf16)bb.w;
    } else {
      #pragma unroll
      for (int k = 0; k < 8; ++k) {
        const int c = c0 + k;
        v[k] = (bf16)((r < R && c < C) ? in[(long)r * C + c] : 0.f);
      }
    }
    *(bf16x8*)&out[(long)r * Cp + c0] = v;
  } else if (b < 20480) {
    const int tb = b - 16384;
    const int r0 = (tb & 63) * 64;
    const int c0 = (tb >> 6) * 64;
    const int row = t >> 2;
    const int seg = (t & 3) * 16;
    const int r = r0 + row;
    #pragma unroll
    for (int q = 0; q < 4; ++q) {
      const int c = c0 + seg + q * 4;
      float4 a;
      if (r < 4000 && c + 3 < 4000) a = *(const float4*)&g.S1[(long)r * 4000 + c];
      else {
        a.x = (r < 4000 && c     < 4000) ? g.S1[(long)r * 4000 + c    ] : 0.f;
        a.y = (r < 4000 && c + 1 < 4000) ? g.S1[(long)r * 4000 + c + 1] : 0.f;
        a.z = (r < 4000 && c + 2 < 4000) ? g.S1[(long)r * 4000 + c + 2] : 0.f;
        a.w = (r < 4000 && c + 3 < 4000) ? g.S1[(long)r * 4000 + c + 3] : 0.f;
      }
      tt[seg + q * 4 + 0][row] = a.x;
      tt[seg + q * 4 + 1][row] = a.y;
      tt[seg + q * 4 + 2][row] = a.z;
      tt[seg + q * 4 + 3][row] = a.w;
    }
    __syncthreads();
    const int orow = t >> 2;
    const int oseg = (t & 3) * 16;
    bf16x8 v0, v1;
    #pragma unroll
    for (int k = 0; k < 8; ++k) {
      v0[k] = (bf16)tt[orow][oseg + k];
      v1[k] = (bf16)tt[orow][oseg + 8 + k];
    }
    *(bf16x8*)&g.S1Tb[(long)(c0 + orow) * 4096 + r0 + oseg] = v0;
    *(bf16x8*)&g.S1Tb[(long)(c0 + orow) * 4096 + r0 + oseg + 8] = v1;
  } else if (b < 21073) {
    const PrepA& a = g.pa;
    const int pb = b - 20480;
    if (pb < 416) {
      int k = 0;
      while (pb >= a.b0[k + 1]) ++k;
      const int i = (pb - a.b0[k]) * 256 + t;
      const int c = i >> a.sh[k], f = i & ((1 << a.sh[k]) - 1);
      float v = (f < a.fin[k]) ? a.src[k][(long)f * a.fout[k] + c] : 0.f;
      a.dst[k][i] = (bf16)v;
    } else if (pb < 480) {
      const int i = (pb - 416) * 256 + t;
      const int c = i >> 7, f = i & 127;
      float s = 0.f;
      if (f < 66) {
        #pragma unroll 16
        for (int k = 0; k < 128; ++k) s += a.E0_1[k * 128 + c] * a.Wb1[f * 128 + k];
      }
      a.We1T1[c * 128 + f] = (bf16)s;
    } else if (pb < 512) {
      const int i = (pb - 480) * 256 + t;
      const int c = i >> 7, f = i & 127;
      float s = 0.f;
      if (f < 66) {
        #pragma unroll 16
        for (int k = 0; k < 64; ++k) s += a.E0g2[k * 64 + c] * a.Wbg2[f * 64 + k];
      }
      a.We1T2[c * 128 + f] = (bf16)s;
    } else if (pb < 576) {
      const int i = (pb - 512) * 256 + t;
      const int j = i >> 7, c = i & 127;
      float s = 0.f;
      #pragma unroll 16
      for (int k = 0; k < 128; ++k) s += a.E0_1[j * 128 + k] * a.E1_1[k * 128 + c];
      a.T1f[j * 128 + c] = s;
    } else if (pb < 592) {
      const int i = (pb - 576) * 256 + t;
      const int j = i >> 6, c = i & 63;
      float s = 0.f;
      #pragma unroll 16
      for (int k = 0; k < 64; ++k) s += a.E0g2[j * 64 + k] * a.E1g2[k * 64 + c];
      a.T2f[j * 64 + c] = s;
    } else {
      if (t < 128) {
        float s = 0.f;
        for (int w = 0; w < 128; ++w) s += a.aw1[w * 128 + t] * a.al1[w];
        a.s1[t] = s;
      } else if (t < 192) {
        const int f = t - 128;
        float s = 0.f;
        for (int w = 0; w < 64; ++w) s += a.aw2[w * 64 + f] * a.al2[w];
        a.s2[f] = s;
      }
    }
  } else {
    const long base = (long)(b - 21073) * 2048 + t * 8;
    const int gn = (int)(base >> 7);
    const int f0 = (int)(base & 127);
    const int z = gn >> 11, n = gn & 2047;
    bf16x8 v;
    #pragma unroll
    for (int k = 0; k < 8; ++k) {
      const int f = f0 + k;
      float val = 0.f;
      if (n < 2000) {
        if (f < 2)       val = g.x[(long)z * 4000 + n * 2 + f];
        else if (f < 66) val = g.h[(long)z * 128000 + (long)n * 64 + (f - 2)];
      }
      v[k] = (bf16)val;
    }
    *(bf16x8*)&g.tem[base] = v;
  }
}

// prep_all2: We2^T = Wb*T (96 blocks).
struct Prep2Args {
  const float* Wb1; const float* Wbg2;
  const float* T1f; const float* T2f;
  bf16* We2T1; bf16* We2T2;
};
__global__ __launch_bounds__(256) void prep_all2(Prep2Args a) {
  const int b = blockIdx.x, t = threadIdx.x;
  if (b < 64) {
    const int i = b * 256 + t;
    const int c = i >> 7, f = i & 127;
    float s = 0.f;
    if (f < 66) {
      #pragma unroll 16
      for (int j = 0; j < 128; ++j) s += a.Wb1[f * 128 + j] * a.T1f[j * 128 + c];
    }
    a.We2T1[c * 128 + f] = (bf16)s;
  } else {
    const int i = (b - 64) * 256 + t;
    const int c = i >> 7, f = i & 127;
    float s = 0.f;
    if (f < 66) {
      #pragma unroll 16
      for (int j = 0; j < 64; ++j) s += a.Wbg2[f * 64 + j] * a.T2f[j * 64 + c];
    }
    a.We2T2[c * 128 + f] = (bf16)s;
  }
}

// g1 attention (F=128) fused with build_tem2.
__global__ void attention_fuse(const bf16* hop0, const bf16* hop1,
                               const bf16* hop2, const float* s,
                               const float* x, const float* h,
                               bf16* fea64, bf16* tem) {
  const int nloc = blockIdx.x * 4 + (threadIdx.x >> 6);
  const int b = blockIdx.y;
  const int lane = threadIdx.x & 63;
  const long bn = (long)b * 2048 + nloc;
  float h0[2], h1[2], h2[2];
  float d0 = 0.f, d1 = 0.f, d2 = 0.f;
  #pragma unroll
  for (int q = 0; q < 2; ++q) {
    const int f = lane + q * 64;
    h0[q] = (float)hop0[bn * 256 + f];
    h1[q] = (float)hop1[bn * 256 + f];
    h2[q] = (float)hop2[bn * 128 + f];
    const float sv = s[f];
    d0 += h0[q] * sv; d1 += h1[q] * sv; d2 += h2[q] * sv;
  }
  #pragma unroll
  for (int o = 32; o; o >>= 1) {
    d0 += __shfl_xor(d0, o); d1 += __shfl_xor(d1, o); d2 += __shfl_xor(d2, o);
  }
  const float mx = fmaxf(d0, fmaxf(d1, d2));
  float e0 = expf(d0 - mx), e1 = expf(d1 - mx), e2 = expf(d2 - mx);
  const float inv = 1.f / (e0 + e1 + e2);
  e0 *= inv; e1 *= inv; e2 *= inv;
  const float o0 = e0 * h0[0] + e1 * h1[0] + e2 * h2[0];
  const float o1 = e0 * h0[1] + e1 * h1[1] + e2 * h2[1];   // r-gate
  fea64[bn * 64 + lane] = (bf16)o0;
  const float r0 = __shfl(o1, (lane >= 2) ? lane - 2 : 0);
  const float r1 = __shfl(o1, (62 + lane) & 63);
  float t0 = 0.f, t1 = 0.f;
  if (nloc < 2000) {
    const long hb = (long)b * 128000 + (long)nloc * 64;
    if (lane < 2) {
      t0 = x[(long)b * 4000 + nloc * 2 + lane];
      t1 = (1.f / (1.f + expf(-r1))) * h[hb + 62 + lane];
    } else {
      t0 = (1.f / (1.f + expf(-r0))) * h[hb + (lane - 2)];
    }
  }
  tem[bn * 128 + lane] = (bf16)t0;
  tem[bn * 128 + 64 + lane] = (bf16)t1;
}

// g2 attention (F=64) fused with gru_out.
__global__ void attention_gru(const bf16* hop0, const bf16* hop1,
                              const bf16* hop2, const float* s,
                              const bf16* fea64, const float* h, float* out) {
  const int nloc = blockIdx.x * 4 + (threadIdx.x >> 6);
  const int b = blockIdx.y;
  const int lane = threadIdx.x & 63;
  const long bn = (long)b * 2048 + nloc;
  const float a0 = (float)hop0[bn * 128 + lane];
  const float a1 = (float)hop1[bn * 128 + lane];
  const float a2 = (float)hop2[bn * 64 + lane];
  const float sv = s[lane];
  float d0 = a0 * sv, d1 = a1 * sv, d2 = a2 * sv;
  #pragma unroll
  for (int o = 32; o; o >>= 1) {
    d0 += __shfl_xor(d0, o); d1 += __shfl_xor(d1, o); d2 += __shfl_xor(d2, o);
  }
  const float mx = fmaxf(d0, fmaxf(d1, d2));
  float e0 = expf(d0 - mx), e1 = expf(d1 - mx), e2 = expf(d2 - mx);
  const float inv = 1.f / (e0 + e1 + e2);
  e0 *= inv; e1 *= inv; e2 *= inv;
  const float c = e0 * a0 + e1 * a1 + e2 * a2;
  if (nloc < 2000) {
    const float z  = (float)fea64[bn * 64 + lane];
    const float hv = h[(long)b * 128000 + (long)nloc * 64 + lane];
    const float zs = 1.f / (1.f + expf(-z));
    out[(long)b * 128000 + (long)nloc * 64 + lane] =
        zs * hv + (1.f - zs) * tanhf(c);
  }
}

__global__ void ws_diag(float* out, int n, float v) {
  int i = blockIdx.x * blockDim.x + threadIdx.x;
  if (i < n) out[i] = v;
}

// ---------------------------------------------------------------------------

static TaskDesc TD(int kind, int gx, int nblk,
                   const bf16* A, int lda,
                   const bf16* B, int ldb, int zshB, long sB,
                   bf16* Cn, int ldcn, long sCn,
                   bf16* Ct, int ldct, long sCt, int zshC, int K) {
  TaskDesc t;
  t.g = GemmArgs{A, B, Cn, Ct, lda, ldb, ldcn, ldct, K, zshB, zshC, sB, sCn, sCt};
  t.kind = kind; t.gx = gx; t.blk0 = 0; t.nblk = nblk;
  return t;
}
static void runT(hipStream_t st, int n, const TaskDesc* ts) {
  MultiArgs m = {};
  int off = 0;
  for (int i = 0; i < n; ++i) { m.t[i] = ts[i]; m.t[i].blk0 = off; off += ts[i].nblk; }
  m.nt = n;
  gemm_multi<<<off, 256, 0, st>>>(m);
}
static void run1(hipStream_t st, TaskDesc a) { runT(st, 1, &a); }
static void run2p(hipStream_t st, TaskDesc a, TaskDesc b) {
  TaskDesc ts[2] = {a, b}; runT(st, 2, ts);
}
static void run3p(hipStream_t st, TaskDesc a, TaskDesc b, TaskDesc c) {
  TaskDesc ts[3] = {a, b, c}; runT(st, 3, ts);
}

extern "C" void kernel_launch(void* const* d_in, const int* in_sizes, int n_in,
                              void* d_out, int out_size, void* d_ws, size_t ws_size,
                              hipStream_t stream) {
  const float* x    = (const float*)d_in[0];
  const float* hid  = (const float*)d_in[1];
  const float* S0   = (const float*)d_in[2];
  const float* S1   = (const float*)d_in[3];
  const float* M    = (const float*)d_in[4];

  char* base = (char*)d_ws;
  size_t off = 0;
  auto alloc = [&](size_t bytes) -> void* {
    void* r = base + off;
    off += (bytes + 255) & ~(size_t)255;
    return r;
  };

  bf16* S0b  = (bf16*)alloc(2048ull * 2048 * 2);   //  8 MB
  bf16* S1b  = (bf16*)alloc(4096ull * 4096 * 2);   // 32 MB
  bf16* S1Tb = (bf16*)alloc(4096ull * 4096 * 2);   // 32 MB
  bf16* Mb   = (bf16*)alloc(2048ull * 4096 * 2);   // 16 MB
  bf16* tem  = (bf16*)alloc(16ull * 2048 * 128 * 2);  // 8 MB

  bf16* WtAll1 = (bf16*)alloc(384 * 128 * 2);
  bf16* W1T    = (bf16*)alloc(128 * 256 * 2);
  bf16* W2T    = (bf16*)alloc(128 * 256 * 2);
  bf16* WtAll2 = (bf16*)alloc(192 * 128 * 2);
  bf16* W1g2T  = (bf16*)alloc(64 * 128 * 2);
  bf16* W2g2T  = (bf16*)alloc(64 * 128 * 2);
  float* s1  = (float*)alloc(128 * 4);
  float* s2  = (float*)alloc(64 * 4);
  float* T1f = (float*)alloc(128 * 128 * 4);
  float* T2f = (float*)alloc(64 * 64 * 4);

  bf16* P1 = (bf16*)alloc(2048ull * 2048 * 2);     //  8 MB
  bf16* P2 = (bf16*)alloc(2048ull * 2048 * 2);     //  8 MB
  bf16* R  = (bf16*)alloc(2048ull * 4096 * 2);     // 16 MB
  bf16* R2 = (bf16*)alloc(2048ull * 4096 * 2);     // 16 MB

  if (off > ws_size) {
    ws_diag<<<4, 256, 0, stream>>>((float*)d_out, 1024, (float)(ws_size >> 20));
    return;
  }

  // Overlays (liveness-audited, identical to r8..r13):
  bf16* xAll   = S1b;
  bf16* cat1   = S1Tb;
  bf16* cat2   = (bf16*)((char*)S1Tb + 16777216);
  bf16* cpb    = S1b;
  bf16* hop2   = (bf16*)((char*)S1b + 8388608);
  bf16* fea64  = (bf16*)((char*)S1b + 16777216);
  bf16* xAll2  = R;
  bf16* cat1_2 = S1Tb;
  bf16* cat2_2 = (bf16*)((char*)S1Tb + 8388608);
  bf16* cpb2   = S1b;
  bf16* hop2_2 = (bf16*)((char*)S1b + 8388608);

  // ---- prep (2 launches) ----
  Prep1Args p1;
  p1.S0 = S0; p1.S1 = S1; p1.M = M;
  p1.S0b = S0b; p1.S1b = S1b; p1.Mb = Mb; p1.S1Tb = S1Tb;
  p1.x = x; p1.h = hid; p1.tem = tem;
  {
    PrepA& pa = p1.pa;
    const float* wsrc[6] = {(const float*)d_in[6], (const float*)d_in[7],
                            (const float*)d_in[8], (const float*)d_in[14],
                            (const float*)d_in[15], (const float*)d_in[16]};
    bf16* wdst[6] = {WtAll1, W1T, W2T, WtAll2, W1g2T, W2g2T};
    static const int wfin[6]  = {66, 256, 256, 66, 128, 128};
    static const int wfout[6] = {128, 128, 128, 64, 64, 64};
    static const int wsh[6]   = {7, 8, 8, 7, 7, 7};
    static const int wb0[7]   = {0, 64, 192, 320, 352, 384, 416};
    for (int i = 0; i < 6; ++i) {
      pa.src[i] = wsrc[i]; pa.dst[i] = wdst[i];
      pa.fin[i] = wfin[i]; pa.fout[i] = wfout[i]; pa.sh[i] = wsh[i];
    }
    for (int i = 0; i < 7; ++i) pa.b0[i] = wb0[i];
    pa.Wb1  = (const float*)d_in[5];  pa.E0_1 = (const float*)d_in[9];
    pa.E1_1 = (const float*)d_in[10];
    pa.Wbg2 = (const float*)d_in[13]; pa.E0g2 = (const float*)d_in[17];
    pa.E1g2 = (const float*)d_in[18];
    pa.We1T1 = WtAll1 + 128 * 128;  pa.We1T2 = WtAll2 + 64 * 128;
    pa.T1f = T1f; pa.T2f = T2f;
    pa.aw1 = (const float*)d_in[11]; pa.al1 = (const float*)d_in[12]; pa.s1 = s1;
    pa.aw2 = (const float*)d_in[19]; pa.al2 = (const float*)d_in[20]; pa.s2 = s2;
  }
  prep_all1<<<23121, 256, 0, stream>>>(p1);
  Prep2Args p2{(const float*)d_in[5], (const float*)d_in[13], T1f, T2f,
               WtAll1 + 256 * 128, WtAll2 + 128 * 128};
  prep_all2<<<96, 256, 0, stream>>>(p2);

  // ---- L1: R = M*S1, R2 = M*S1^T ----
  run2p(stream,
    TD(0, 16, 512, Mb,4096, S1Tb,4096,12,0, R,4096,0,  nullptr,0,0, 12, 4096),
    TD(0, 16, 512, Mb,4096, S1b,4096,12,0,  R2,4096,0, nullptr,0,0, 12, 4096));
  // ---- L2: P1 = R*M^T, P2 = R*R2^T, xAll proj (co-resident 2/CU) ----
  run3p(stream,
    TD(0, 16, 256, R,4096, Mb,4096,11,0, P1,2048,0, nullptr,0,0, 11, 4096),
    TD(0, 16, 256, R,4096, R2,4096,11,0, P2,2048,0, nullptr,0,0, 11, 4096),
    TD(0, 3, 768, WtAll1,128, tem,128,11,2048L*128,
       xAll,2048,384L*2048, nullptr,0,0, 11, 128));
  // ---- L3: cat1 = [S0*xW0 | P1*xe1], cat2_hi = P2*xe2 ----
  run3p(stream,
    TD(0, 16, 256, S0b,2048, xAll,2048,7,384L*2048,
       cat1,256,2048L*256, nullptr,0,0, 7, 2048),
    TD(0, 16, 256, P1,2048, xAll+128*2048,2048,7,384L*2048,
       cat1+128,256,2048L*256, nullptr,0,0, 7, 2048),
    TD(0, 16, 256, P2,2048, xAll+256*2048,2048,7,384L*2048,
       cat2+128,256,2048L*256, nullptr,0,0, 7, 2048));
  // ---- L4-L7: serial g1 tail (r13 form, 512-block) ----
  run1(stream, TD(2, 1, 512, W1T,256, cat1,256,11,2048L*256,
                  cpb,2048,128L*2048, nullptr,0,0, 11, 256));
  run1(stream, TD(2, 16, 512, S0b,2048, cpb,2048,7,128L*2048,
                  cat2,256,2048L*256, nullptr,0,0, 7, 2048));
  run1(stream, TD(2, 1, 512, W2T,256, cat2,256,11,2048L*256,
                  cpb,2048,128L*2048, nullptr,0,0, 11, 256));
  run1(stream, TD(2, 16, 512, S0b,2048, cpb,2048,7,128L*2048,
                  hop2,128,2048L*128, nullptr,0,0, 7, 2048));
  attention_fuse<<<dim3(512, 16), 256, 0, stream>>>(cat1, cat2, hop2, s1,
                                                    x, hid, fea64, tem);

  // ---- L8: g2 projection ----
  run1(stream, TD(1, 3, 768, WtAll2,128, tem,128,11,2048L*128,
                  xAll2,2048,192L*2048, nullptr,0,0, 11, 128));
  // ---- L9: g2 leading aggs (kind2, r13 form) ----
  run3p(stream,
    TD(2, 16, 256, S0b,2048, xAll2,2048,6,192L*2048,
       cat1_2,128,2048L*128, nullptr,0,0, 6, 2048),
    TD(2, 16, 256, P1,2048, xAll2+64*2048,2048,6,192L*2048,
       cat1_2+64,128,2048L*128, nullptr,0,0, 6, 2048),
    TD(2, 16, 256, P2,2048, xAll2+128*2048,2048,6,192L*2048,
       cat2_2+64,128,2048L*128, nullptr,0,0, 6, 2048));
  // ---- L10-L13: serial g2 tail (L11/L13 kind3 512, r14-validated form) ----
  run1(stream, TD(3, 1, 512, W1g2T,128, cat1_2,128,11,2048L*128,
                  cpb2,2048,64L*2048, nullptr,0,0, 11, 128));
  run1(stream, TD(3, 32, 512, S0b,2048, cpb2,2048,6,64L*2048,
                  cat2_2,128,2048L*128, nullptr,0,0, 6, 2048));
  run1(stream, TD(3, 1, 512, W2g2T,128, cat2_2,128,11,2048L*128,
                  cpb2,2048,64L*2048, nullptr,0,0, 11, 128));
  run1(stream, TD(3, 32, 512, S0b,2048, cpb2,2048,6,64L*2048,
                  hop2_2,64,2048L*64, nullptr,0,0, 6, 2048));
  attention_gru<<<dim3(512, 16), 256, 0, stream>>>(cat1_2, cat2_2, hop2_2, s2,
                                                   fea64, hid, (float*)d_out);
}

// Round 16
// 491.464 us; speedup vs baseline: 1.1251x; 1.0375x over previous
//
#include <hip/hip_runtime.h>
#include <stdint.h>

// ---------------------------------------------------------------------------
// BGCGRU on MI355X. Round 16: per-launch LDS sizing (templated smem).
//   kind0 needs 64KB; kind1/kind2 need 48KB; kind3 needs 32KB. Smaller LDS
//   raises the residency cap (2 -> 3 -> 5 blocks/CU); audit shows L8 (768
//   blocks, kind1) and L9 (768 blocks, kind2x3) gain full co-residency.
// Everything else byte-identical to r15 (509.9 us best).
// ---------------------------------------------------------------------------

typedef __bf16 bf16;
typedef float  f32x4  __attribute__((ext_vector_type(4)));
typedef __bf16 bf16x8 __attribute__((ext_vector_type(8)));
typedef __bf16 bf16x4v __attribute__((ext_vector_type(4)));

#define DEVI __device__ __forceinline__

DEVI void gload16(const bf16* g, bf16* l) {
  __builtin_amdgcn_global_load_lds(
      (const __attribute__((address_space(1))) void*)g,
      (__attribute__((address_space(3))) void*)l, 16, 0, 0);
}

struct GemmArgs {
  const bf16* A; const bf16* B;
  bf16* Cn;   // normal write:  [z] row-major [m][col], nullable
  bf16* Ct;   // transposed:    [z] row-major [col][m], nullable
  int lda, ldb, ldcn, ldct, K, zshB, zshC;
  long sB, sCn, sCt;   // per-z element strides
};

struct TaskDesc { GemmArgs g; int kind, gx, blk0, nblk; };
struct MultiArgs { TaskDesc t[3]; int nt; };

// 2-phase double-buffered NT GEMM, BK=64. 4 waves (2x2), 16x16x32 bf16 MFMA.
template<int BM, int BN>
DEVI void gemm_body(const GemmArgs& g, int bx, int by, bf16* smem) {
  constexpr int BK  = 64;
  constexpr int ASZ = BM * BK, BSZ = BN * BK;
  bf16* Abuf = smem;
  bf16* Bbuf = smem + 2 * ASZ;
  const int tid  = threadIdx.x;
  const int wave = tid >> 6;
  const int lane = tid & 63;
  const int wm = (wave >> 1) * (BM / 2);
  const int wn = (wave & 1) * (BN / 2);
  constexpr int FM = BM / 32;
  constexpr int FN = BN / 32;

  const int sseg = (((tid & 7) ^ ((tid >> 3) & 7))) * 8;  // swz source seg
  const int l15  = lane & 15;
  const int lq   = lane >> 4;

  const bf16* arow[BM / 32];
  #pragma unroll
  for (int c = 0; c < BM / 32; ++c)
    arow[c] = g.A + (long)(bx * BM + c * 32 + (tid >> 3)) * g.lda + sseg;
  const bf16* brow[BN / 32];
  const int maskB = (1 << g.zshB) - 1;
  #pragma unroll
  for (int c = 0; c < BN / 32; ++c) {
    const int nb = by * BN + c * 32 + (tid >> 3);
    brow[c] = g.B + (long)(nb >> g.zshB) * g.sB + (long)(nb & maskB) * g.ldb + sseg;
  }

  f32x4 acc[FM][FN] = {};

  auto stage = [&](int buf, int kt) {
    #pragma unroll
    for (int c = 0; c < BM / 32; ++c)
      gload16(arow[c] + kt, &Abuf[buf * ASZ + c * 2048 + tid * 8]);
    #pragma unroll
    for (int c = 0; c < BN / 32; ++c)
      gload16(brow[c] + kt, &Bbuf[buf * BSZ + c * 2048 + tid * 8]);
  };
  auto compute = [&](int cb) {
    #pragma unroll
    for (int kk = 0; kk < 2; ++kk) {
      bf16x8 af[FM], bfr[FN];
      #pragma unroll
      for (int i = 0; i < FM; ++i) {
        const int R = wm + i * 16 + l15;
        af[i] = *(const bf16x8*)
            &Abuf[cb * ASZ + R * 64 + ((kk * 4 + lq) ^ (l15 & 7)) * 8];
      }
      #pragma unroll
      for (int j = 0; j < FN; ++j) {
        const int R = wn + j * 16 + l15;
        bfr[j] = *(const bf16x8*)
            &Bbuf[cb * BSZ + R * 64 + ((kk * 4 + lq) ^ (l15 & 7)) * 8];
      }
      #pragma unroll
      for (int i = 0; i < FM; ++i)
        #pragma unroll
        for (int j = 0; j < FN; ++j)
          acc[i][j] = __builtin_amdgcn_mfma_f32_16x16x32_bf16(af[i], bfr[j],
                                                              acc[i][j], 0, 0, 0);
    }
  };

  const int nt = g.K / BK;
  stage(0, 0);
  __syncthreads();
  int cur = 0;
  for (int t = 0; t < nt; ++t) {
    if (t + 1 < nt) stage(cur ^ 1, (t + 1) * BK);
    compute(cur);
    __syncthreads();
    cur ^= 1;
  }

  const int gm0 = bx * BM + wm;
  const int gn0 = by * BN + wn;
  const int rowq = lq * 4;
  const int maskC = (1 << g.zshC) - 1;
  if (g.Cn) {
    #pragma unroll
    for (int i = 0; i < FM; ++i)
      #pragma unroll
      for (int j = 0; j < FN; ++j) {
        const int m0 = gm0 + i * 16 + rowq;
        const int ng = gn0 + j * 16 + l15;
        bf16* Cz = g.Cn + (long)(ng >> g.zshC) * g.sCn + (ng & maskC);
        #pragma unroll
        for (int r = 0; r < 4; ++r)
          Cz[(long)(m0 + r) * g.ldcn] = (bf16)acc[i][j][r];
      }
  }
  if (g.Ct) {
    #pragma unroll
    for (int i = 0; i < FM; ++i)
      #pragma unroll
      for (int j = 0; j < FN; ++j) {
        const int m0 = gm0 + i * 16 + rowq;
        const int ng = gn0 + j * 16 + l15;
        bf16x4v v = { (bf16)acc[i][j][0], (bf16)acc[i][j][1],
                      (bf16)acc[i][j][2], (bf16)acc[i][j][3] };
        *(bf16x4v*)(g.Ct + (long)(ng >> g.zshC) * g.sCt
                    + (long)(ng & maskC) * g.ldct + m0) = v;
      }
  }
}

template<int SME>
__global__ __launch_bounds__(256) void gemm_multi_t(MultiArgs mu) {
  __shared__ bf16 smem[SME];
  const int b = blockIdx.x;
  int ti = 0;
  if (mu.nt > 1 && b >= mu.t[1].blk0) ti = 1;
  if (mu.nt > 2 && b >= mu.t[2].blk0) ti = 2;
  const TaskDesc t = mu.t[ti];
  const int local = b - t.blk0;
  int bx, by;
  if ((t.gx & 7) == 0) {
    const int xcd = local & 7;
    const int idx = local >> 3;
    const int sub = t.gx >> 3;
    bx = xcd * sub + idx % sub;
    by = idx / sub;
  } else {
    bx = local % t.gx;
    by = local / t.gx;
  }
  if (t.kind == 0) {
    if (SME >= 32768) gemm_body<128, 128>(t.g, bx, by, smem);
  } else if (t.kind == 1) {
    if (SME >= 24576) gemm_body< 64, 128>(t.g, bx, by, smem);
  } else if (t.kind == 2) {
    if (SME >= 24576) gemm_body<128,  64>(t.g, bx, by, smem);
  } else {
    gemm_body< 64,  64>(t.g, bx, by, smem);
  }
}

// ---------------- prep / elementwise kernels -------------------------------

struct PrepA {
  const float* src[6]; bf16* dst[6]; int fin[6], fout[6], sh[6], b0[7];
  const float* Wb1;  const float* E0_1; const float* E1_1;
  const float* Wbg2; const float* E0g2; const float* E1g2;
  bf16* We1T1; bf16* We1T2; float* T1f; float* T2f;
  const float* aw1; const float* al1; float* s1;
  const float* aw2; const float* al2; float* s2;
};

// prep_all1: [0,16384) pads; [16384,20480) S1 transpose; [20480,21073) prep_a;
//            [21073,23121) tem1 build.
struct Prep1Args {
  const float* S0; const float* S1; const float* M;
  bf16* S0b; bf16* S1b; bf16* Mb; bf16* S1Tb;
  const float* x; const float* h; bf16* tem;
  PrepA pa;
};
__global__ __launch_bounds__(256) void prep_all1(Prep1Args g) {
  __shared__ float tt[64][65];
  const int b = blockIdx.x, t = threadIdx.x;
  if (b < 16384) {
    const int y = b >> 1;
    const int c0 = ((b & 1) * 256 + t) * 8;
    const float* in; bf16* out; int R, C, Cp, r;
    if (y < 2048)      { in = g.S0; out = g.S0b; R = 2000; C = 2000; Cp = 2048; r = y; }
    else if (y < 6144) { in = g.S1; out = g.S1b; R = 4000; C = 4000; Cp = 4096; r = y - 2048; }
    else               { in = g.M;  out = g.Mb;  R = 2000; C = 4000; Cp = 4096; r = y - 6144; }
    if (c0 >= Cp) return;
    bf16x8 v;
    if (r < R && c0 + 7 < C) {
      const float4 a = *(const float4*)&in[(long)r * C + c0];
      const float4 bb = *(const float4*)&in[(long)r * C + c0 + 4];
      v[0]=(bf16)a.x; v[1]=(bf16)a.y; v[2]=(bf16)a.z; v[3]=(bf16)a.w;
      v[4]=(bf16)bb.x; v[5]=(bf16)bb.y; v[6]=(bf16)bb.z; v[7]=(bf16)bb.w;
    } else {
      #pragma unroll
      for (int k = 0; k < 8; ++k) {
        const int c = c0 + k;
        v[k] = (bf16)((r < R && c < C) ? in[(long)r * C + c] : 0.f);
      }
    }
    *(bf16x8*)&out[(long)r * Cp + c0] = v;
  } else if (b < 20480) {
    const int tb = b - 16384;
    const int r0 = (tb & 63) * 64;
    const int c0 = (tb >> 6) * 64;
    const int row = t >> 2;
    const int seg = (t & 3) * 16;
    const int r = r0 + row;
    #pragma unroll
    for (int q = 0; q < 4; ++q) {
      const int c = c0 + seg + q * 4;
      float4 a;
      if (r < 4000 && c + 3 < 4000) a = *(const float4*)&g.S1[(long)r * 4000 + c];
      else {
        a.x = (r < 4000 && c     < 4000) ? g.S1[(long)r * 4000 + c    ] : 0.f;
        a.y = (r < 4000 && c + 1 < 4000) ? g.S1[(long)r * 4000 + c + 1] : 0.f;
        a.z = (r < 4000 && c + 2 < 4000) ? g.S1[(long)r * 4000 + c + 2] : 0.f;
        a.w = (r < 4000 && c + 3 < 4000) ? g.S1[(long)r * 4000 + c + 3] : 0.f;
      }
      tt[seg + q * 4 + 0][row] = a.x;
      tt[seg + q * 4 + 1][row] = a.y;
      tt[seg + q * 4 + 2][row] = a.z;
      tt[seg + q * 4 + 3][row] = a.w;
    }
    __syncthreads();
    const int orow = t >> 2;
    const int oseg = (t & 3) * 16;
    bf16x8 v0, v1;
    #pragma unroll
    for (int k = 0; k < 8; ++k) {
      v0[k] = (bf16)tt[orow][oseg + k];
      v1[k] = (bf16)tt[orow][oseg + 8 + k];
    }
    *(bf16x8*)&g.S1Tb[(long)(c0 + orow) * 4096 + r0 + oseg] = v0;
    *(bf16x8*)&g.S1Tb[(long)(c0 + orow) * 4096 + r0 + oseg + 8] = v1;
  } else if (b < 21073) {
    const PrepA& a = g.pa;
    const int pb = b - 20480;
    if (pb < 416) {
      int k = 0;
      while (pb >= a.b0[k + 1]) ++k;
      const int i = (pb - a.b0[k]) * 256 + t;
      const int c = i >> a.sh[k], f = i & ((1 << a.sh[k]) - 1);
      float v = (f < a.fin[k]) ? a.src[k][(long)f * a.fout[k] + c] : 0.f;
      a.dst[k][i] = (bf16)v;
    } else if (pb < 480) {
      const int i = (pb - 416) * 256 + t;
      const int c = i >> 7, f = i & 127;
      float s = 0.f;
      if (f < 66) {
        #pragma unroll 16
        for (int k = 0; k < 128; ++k) s += a.E0_1[k * 128 + c] * a.Wb1[f * 128 + k];
      }
      a.We1T1[c * 128 + f] = (bf16)s;
    } else if (pb < 512) {
      const int i = (pb - 480) * 256 + t;
      const int c = i >> 7, f = i & 127;
      float s = 0.f;
      if (f < 66) {
        #pragma unroll 16
        for (int k = 0; k < 64; ++k) s += a.E0g2[k * 64 + c] * a.Wbg2[f * 64 + k];
      }
      a.We1T2[c * 128 + f] = (bf16)s;
    } else if (pb < 576) {
      const int i = (pb - 512) * 256 + t;
      const int j = i >> 7, c = i & 127;
      float s = 0.f;
      #pragma unroll 16
      for (int k = 0; k < 128; ++k) s += a.E0_1[j * 128 + k] * a.E1_1[k * 128 + c];
      a.T1f[j * 128 + c] = s;
    } else if (pb < 592) {
      const int i = (pb - 576) * 256 + t;
      const int j = i >> 6, c = i & 63;
      float s = 0.f;
      #pragma unroll 16
      for (int k = 0; k < 64; ++k) s += a.E0g2[j * 64 + k] * a.E1g2[k * 64 + c];
      a.T2f[j * 64 + c] = s;
    } else {
      if (t < 128) {
        float s = 0.f;
        for (int w = 0; w < 128; ++w) s += a.aw1[w * 128 + t] * a.al1[w];
        a.s1[t] = s;
      } else if (t < 192) {
        const int f = t - 128;
        float s = 0.f;
        for (int w = 0; w < 64; ++w) s += a.aw2[w * 64 + f] * a.al2[w];
        a.s2[f] = s;
      }
    }
  } else {
    const long base = (long)(b - 21073) * 2048 + t * 8;
    const int gn = (int)(base >> 7);
    const int f0 = (int)(base & 127);
    const int z = gn >> 11, n = gn & 2047;
    bf16x8 v;
    #pragma unroll
    for (int k = 0; k < 8; ++k) {
      const int f = f0 + k;
      float val = 0.f;
      if (n < 2000) {
        if (f < 2)       val = g.x[(long)z * 4000 + n * 2 + f];
        else if (f < 66) val = g.h[(long)z * 128000 + (long)n * 64 + (f - 2)];
      }
      v[k] = (bf16)val;
    }
    *(bf16x8*)&g.tem[base] = v;
  }
}

// prep_all2: We2^T = Wb*T (96 blocks).
struct Prep2Args {
  const float* Wb1; const float* Wbg2;
  const float* T1f; const float* T2f;
  bf16* We2T1; bf16* We2T2;
};
__global__ __launch_bounds__(256) void prep_all2(Prep2Args a) {
  const int b = blockIdx.x, t = threadIdx.x;
  if (b < 64) {
    const int i = b * 256 + t;
    const int c = i >> 7, f = i & 127;
    float s = 0.f;
    if (f < 66) {
      #pragma unroll 16
      for (int j = 0; j < 128; ++j) s += a.Wb1[f * 128 + j] * a.T1f[j * 128 + c];
    }
    a.We2T1[c * 128 + f] = (bf16)s;
  } else {
    const int i = (b - 64) * 256 + t;
    const int c = i >> 7, f = i & 127;
    float s = 0.f;
    if (f < 66) {
      #pragma unroll 16
      for (int j = 0; j < 64; ++j) s += a.Wbg2[f * 64 + j] * a.T2f[j * 64 + c];
    }
    a.We2T2[c * 128 + f] = (bf16)s;
  }
}

// g1 attention (F=128) fused with build_tem2.
__global__ void attention_fuse(const bf16* hop0, const bf16* hop1,
                               const bf16* hop2, const float* s,
                               const float* x, const float* h,
                               bf16* fea64, bf16* tem) {
  const int nloc = blockIdx.x * 4 + (threadIdx.x >> 6);
  const int b = blockIdx.y;
  const int lane = threadIdx.x & 63;
  const long bn = (long)b * 2048 + nloc;
  float h0[2], h1[2], h2[2];
  float d0 = 0.f, d1 = 0.f, d2 = 0.f;
  #pragma unroll
  for (int q = 0; q < 2; ++q) {
    const int f = lane + q * 64;
    h0[q] = (float)hop0[bn * 256 + f];
    h1[q] = (float)hop1[bn * 256 + f];
    h2[q] = (float)hop2[bn * 128 + f];
    const float sv = s[f];
    d0 += h0[q] * sv; d1 += h1[q] * sv; d2 += h2[q] * sv;
  }
  #pragma unroll
  for (int o = 32; o; o >>= 1) {
    d0 += __shfl_xor(d0, o); d1 += __shfl_xor(d1, o); d2 += __shfl_xor(d2, o);
  }
  const float mx = fmaxf(d0, fmaxf(d1, d2));
  float e0 = expf(d0 - mx), e1 = expf(d1 - mx), e2 = expf(d2 - mx);
  const float inv = 1.f / (e0 + e1 + e2);
  e0 *= inv; e1 *= inv; e2 *= inv;
  const float o0 = e0 * h0[0] + e1 * h1[0] + e2 * h2[0];
  const float o1 = e0 * h0[1] + e1 * h1[1] + e2 * h2[1];   // r-gate
  fea64[bn * 64 + lane] = (bf16)o0;
  const float r0 = __shfl(o1, (lane >= 2) ? lane - 2 : 0);
  const float r1 = __shfl(o1, (62 + lane) & 63);
  float t0 = 0.f, t1 = 0.f;
  if (nloc < 2000) {
    const long hb = (long)b * 128000 + (long)nloc * 64;
    if (lane < 2) {
      t0 = x[(long)b * 4000 + nloc * 2 + lane];
      t1 = (1.f / (1.f + expf(-r1))) * h[hb + 62 + lane];
    } else {
      t0 = (1.f / (1.f + expf(-r0))) * h[hb + (lane - 2)];
    }
  }
  tem[bn * 128 + lane] = (bf16)t0;
  tem[bn * 128 + 64 + lane] = (bf16)t1;
}

// g2 attention (F=64) fused with gru_out.
__global__ void attention_gru(const bf16* hop0, const bf16* hop1,
                              const bf16* hop2, const float* s,
                              const bf16* fea64, const float* h, float* out) {
  const int nloc = blockIdx.x * 4 + (threadIdx.x >> 6);
  const int b = blockIdx.y;
  const int lane = threadIdx.x & 63;
  const long bn = (long)b * 2048 + nloc;
  const float a0 = (float)hop0[bn * 128 + lane];
  const float a1 = (float)hop1[bn * 128 + lane];
  const float a2 = (float)hop2[bn * 64 + lane];
  const float sv = s[lane];
  float d0 = a0 * sv, d1 = a1 * sv, d2 = a2 * sv;
  #pragma unroll
  for (int o = 32; o; o >>= 1) {
    d0 += __shfl_xor(d0, o); d1 += __shfl_xor(d1, o); d2 += __shfl_xor(d2, o);
  }
  const float mx = fmaxf(d0, fmaxf(d1, d2));
  float e0 = expf(d0 - mx), e1 = expf(d1 - mx), e2 = expf(d2 - mx);
  const float inv = 1.f / (e0 + e1 + e2);
  e0 *= inv; e1 *= inv; e2 *= inv;
  const float c = e0 * a0 + e1 * a1 + e2 * a2;
  if (nloc < 2000) {
    const float z  = (float)fea64[bn * 64 + lane];
    const float hv = h[(long)b * 128000 + (long)nloc * 64 + lane];
    const float zs = 1.f / (1.f + expf(-z));
    out[(long)b * 128000 + (long)nloc * 64 + lane] =
        zs * hv + (1.f - zs) * tanhf(c);
  }
}

__global__ void ws_diag(float* out, int n, float v) {
  int i = blockIdx.x * blockDim.x + threadIdx.x;
  if (i < n) out[i] = v;
}

// ---------------------------------------------------------------------------

static TaskDesc TD(int kind, int gx, int nblk,
                   const bf16* A, int lda,
                   const bf16* B, int ldb, int zshB, long sB,
                   bf16* Cn, int ldcn, long sCn,
                   bf16* Ct, int ldct, long sCt, int zshC, int K) {
  TaskDesc t;
  t.g = GemmArgs{A, B, Cn, Ct, lda, ldb, ldcn, ldct, K, zshB, zshC, sB, sCn, sCt};
  t.kind = kind; t.gx = gx; t.blk0 = 0; t.nblk = nblk;
  return t;
}
static void runT(hipStream_t st, int n, const TaskDesc* ts) {
  MultiArgs m = {};
  int off = 0, req = 0;
  static const int kreq[4] = {32768, 24576, 24576, 16384};
  for (int i = 0; i < n; ++i) {
    m.t[i] = ts[i]; m.t[i].blk0 = off; off += ts[i].nblk;
    if (kreq[ts[i].kind] > req) req = kreq[ts[i].kind];
  }
  m.nt = n;
  if (req <= 16384)      gemm_multi_t<16384><<<off, 256, 0, st>>>(m);  // 32 KB
  else if (req <= 24576) gemm_multi_t<24576><<<off, 256, 0, st>>>(m);  // 48 KB
  else                   gemm_multi_t<32768><<<off, 256, 0, st>>>(m);  // 64 KB
}
static void run1(hipStream_t st, TaskDesc a) { runT(st, 1, &a); }
static void run2p(hipStream_t st, TaskDesc a, TaskDesc b) {
  TaskDesc ts[2] = {a, b}; runT(st, 2, ts);
}
static void run3p(hipStream_t st, TaskDesc a, TaskDesc b, TaskDesc c) {
  TaskDesc ts[3] = {a, b, c}; runT(st, 3, ts);
}

extern "C" void kernel_launch(void* const* d_in, const int* in_sizes, int n_in,
                              void* d_out, int out_size, void* d_ws, size_t ws_size,
                              hipStream_t stream) {
  const float* x    = (const float*)d_in[0];
  const float* hid  = (const float*)d_in[1];
  const float* S0   = (const float*)d_in[2];
  const float* S1   = (const float*)d_in[3];
  const float* M    = (const float*)d_in[4];

  char* base = (char*)d_ws;
  size_t off = 0;
  auto alloc = [&](size_t bytes) -> void* {
    void* r = base + off;
    off += (bytes + 255) & ~(size_t)255;
    return r;
  };

  bf16* S0b  = (bf16*)alloc(2048ull * 2048 * 2);   //  8 MB
  bf16* S1b  = (bf16*)alloc(4096ull * 4096 * 2);   // 32 MB
  bf16* S1Tb = (bf16*)alloc(4096ull * 4096 * 2);   // 32 MB
  bf16* Mb   = (bf16*)alloc(2048ull * 4096 * 2);   // 16 MB
  bf16* tem  = (bf16*)alloc(16ull * 2048 * 128 * 2);  // 8 MB

  bf16* WtAll1 = (bf16*)alloc(384 * 128 * 2);
  bf16* W1T    = (bf16*)alloc(128 * 256 * 2);
  bf16* W2T    = (bf16*)alloc(128 * 256 * 2);
  bf16* WtAll2 = (bf16*)alloc(192 * 128 * 2);
  bf16* W1g2T  = (bf16*)alloc(64 * 128 * 2);
  bf16* W2g2T  = (bf16*)alloc(64 * 128 * 2);
  float* s1  = (float*)alloc(128 * 4);
  float* s2  = (float*)alloc(64 * 4);
  float* T1f = (float*)alloc(128 * 128 * 4);
  float* T2f = (float*)alloc(64 * 64 * 4);

  bf16* P1 = (bf16*)alloc(2048ull * 2048 * 2);     //  8 MB
  bf16* P2 = (bf16*)alloc(2048ull * 2048 * 2);     //  8 MB
  bf16* R  = (bf16*)alloc(2048ull * 4096 * 2);     // 16 MB
  bf16* R2 = (bf16*)alloc(2048ull * 4096 * 2);     // 16 MB

  if (off > ws_size) {
    ws_diag<<<4, 256, 0, stream>>>((float*)d_out, 1024, (float)(ws_size >> 20));
    return;
  }

  // Overlays (liveness-audited, identical to r8..r15):
  bf16* xAll   = S1b;
  bf16* cat1   = S1Tb;
  bf16* cat2   = (bf16*)((char*)S1Tb + 16777216);
  bf16* cpb    = S1b;
  bf16* hop2   = (bf16*)((char*)S1b + 8388608);
  bf16* fea64  = (bf16*)((char*)S1b + 16777216);
  bf16* xAll2  = R;
  bf16* cat1_2 = S1Tb;
  bf16* cat2_2 = (bf16*)((char*)S1Tb + 8388608);
  bf16* cpb2   = S1b;
  bf16* hop2_2 = (bf16*)((char*)S1b + 8388608);

  // ---- prep (2 launches) ----
  Prep1Args p1;
  p1.S0 = S0; p1.S1 = S1; p1.M = M;
  p1.S0b = S0b; p1.S1b = S1b; p1.Mb = Mb; p1.S1Tb = S1Tb;
  p1.x = x; p1.h = hid; p1.tem = tem;
  {
    PrepA& pa = p1.pa;
    const float* wsrc[6] = {(const float*)d_in[6], (const float*)d_in[7],
                            (const float*)d_in[8], (const float*)d_in[14],
                            (const float*)d_in[15], (const float*)d_in[16]};
    bf16* wdst[6] = {WtAll1, W1T, W2T, WtAll2, W1g2T, W2g2T};
    static const int wfin[6]  = {66, 256, 256, 66, 128, 128};
    static const int wfout[6] = {128, 128, 128, 64, 64, 64};
    static const int wsh[6]   = {7, 8, 8, 7, 7, 7};
    static const int wb0[7]   = {0, 64, 192, 320, 352, 384, 416};
    for (int i = 0; i < 6; ++i) {
      pa.src[i] = wsrc[i]; pa.dst[i] = wdst[i];
      pa.fin[i] = wfin[i]; pa.fout[i] = wfout[i]; pa.sh[i] = wsh[i];
    }
    for (int i = 0; i < 7; ++i) pa.b0[i] = wb0[i];
    pa.Wb1  = (const float*)d_in[5];  pa.E0_1 = (const float*)d_in[9];
    pa.E1_1 = (const float*)d_in[10];
    pa.Wbg2 = (const float*)d_in[13]; pa.E0g2 = (const float*)d_in[17];
    pa.E1g2 = (const float*)d_in[18];
    pa.We1T1 = WtAll1 + 128 * 128;  pa.We1T2 = WtAll2 + 64 * 128;
    pa.T1f = T1f; pa.T2f = T2f;
    pa.aw1 = (const float*)d_in[11]; pa.al1 = (const float*)d_in[12]; pa.s1 = s1;
    pa.aw2 = (const float*)d_in[19]; pa.al2 = (const float*)d_in[20]; pa.s2 = s2;
  }
  prep_all1<<<23121, 256, 0, stream>>>(p1);
  Prep2Args p2{(const float*)d_in[5], (const float*)d_in[13], T1f, T2f,
               WtAll1 + 256 * 128, WtAll2 + 128 * 128};
  prep_all2<<<96, 256, 0, stream>>>(p2);

  // ---- L1: R = M*S1, R2 = M*S1^T ----
  run2p(stream,
    TD(0, 16, 512, Mb,4096, S1Tb,4096,12,0, R,4096,0,  nullptr,0,0, 12, 4096),
    TD(0, 16, 512, Mb,4096, S1b,4096,12,0,  R2,4096,0, nullptr,0,0, 12, 4096));
  // ---- L2: P1 = R*M^T, P2 = R*R2^T, xAll proj (co-resident 2/CU) ----
  run3p(stream,
    TD(0, 16, 256, R,4096, Mb,4096,11,0, P1,2048,0, nullptr,0,0, 11, 4096),
    TD(0, 16, 256, R,4096, R2,4096,11,0, P2,2048,0, nullptr,0,0, 11, 4096),
    TD(0, 3, 768, WtAll1,128, tem,128,11,2048L*128,
       xAll,2048,384L*2048, nullptr,0,0, 11, 128));
  // ---- L3: cat1 = [S0*xW0 | P1*xe1], cat2_hi = P2*xe2 ----
  run3p(stream,
    TD(0, 16, 256, S0b,2048, xAll,2048,7,384L*2048,
       cat1,256,2048L*256, nullptr,0,0, 7, 2048),
    TD(0, 16, 256, P1,2048, xAll+128*2048,2048,7,384L*2048,
       cat1+128,256,2048L*256, nullptr,0,0, 7, 2048),
    TD(0, 16, 256, P2,2048, xAll+256*2048,2048,7,384L*2048,
       cat2+128,256,2048L*256, nullptr,0,0, 7, 2048));
  // ---- L4-L7: serial g1 tail (512-block; 48 KB LDS -> 3/CU headroom) ----
  run1(stream, TD(2, 1, 512, W1T,256, cat1,256,11,2048L*256,
                  cpb,2048,128L*2048, nullptr,0,0, 11, 256));
  run1(stream, TD(2, 16, 512, S0b,2048, cpb,2048,7,128L*2048,
                  cat2,256,2048L*256, nullptr,0,0, 7, 2048));
  run1(stream, TD(2, 1, 512, W2T,256, cat2,256,11,2048L*256,
                  cpb,2048,128L*2048, nullptr,0,0, 11, 256));
  run1(stream, TD(2, 16, 512, S0b,2048, cpb,2048,7,128L*2048,
                  hop2,128,2048L*128, nullptr,0,0, 7, 2048));
  attention_fuse<<<dim3(512, 16), 256, 0, stream>>>(cat1, cat2, hop2, s1,
                                                    x, hid, fea64, tem);

  // ---- L8: g2 projection (768 blocks; 48 KB -> all co-resident) ----
  run1(stream, TD(1, 3, 768, WtAll2,128, tem,128,11,2048L*128,
                  xAll2,2048,192L*2048, nullptr,0,0, 11, 128));
  // ---- L9: g2 leading aggs (768 blocks; 48 KB -> all co-resident) ----
  run3p(stream,
    TD(2, 16, 256, S0b,2048, xAll2,2048,6,192L*2048,
       cat1_2,128,2048L*128, nullptr,0,0, 6, 2048),
    TD(2, 16, 256, P1,2048, xAll2+64*2048,2048,6,192L*2048,
       cat1_2+64,128,2048L*128, nullptr,0,0, 6, 2048),
    TD(2, 16, 256, P2,2048, xAll2+128*2048,2048,6,192L*2048,
       cat2_2+64,128,2048L*128, nullptr,0,0, 6, 2048));
  // ---- L10-L13: serial g2 tail (kind3, 32 KB LDS) ----
  run1(stream, TD(3, 1, 512, W1g2T,128, cat1_2,128,11,2048L*128,
                  cpb2,2048,64L*2048, nullptr,0,0, 11, 128));
  run1(stream, TD(3, 32, 512, S0b,2048, cpb2,2048,6,64L*2048,
                  cat2_2,128,2048L*128, nullptr,0,0, 6, 2048));
  run1(stream, TD(3, 1, 512, W2g2T,128, cat2_2,128,11,2048L*128,
                  cpb2,2048,64L*2048, nullptr,0,0, 11, 128));
  run1(stream, TD(3, 32, 512, S0b,2048, cpb2,2048,6,64L*2048,
                  hop2_2,64,2048L*64, nullptr,0,0, 6, 2048));
  attention_gru<<<dim3(512, 16), 256, 0, stream>>>(cat1_2, cat2_2, hop2_2, s2,
                                                   fea64, hid, (float*)d_out);
}

// Round 17
// 486.480 us; speedup vs baseline: 1.1366x; 1.0102x over previous
//
#include <hip/hip_runtime.h>
#include <stdint.h>

// ---------------------------------------------------------------------------
// BGCGRU on MI355X. Round 17: prep traffic fix on r16 (491.5 us best).
//   S1 was read twice (pad + transpose). The transpose branch now also emits
//   the straight-padded S1b write (64 MB fewer HBM reads); pad branch drops
//   S1 and its no-op blocks. Everything else byte-identical to r16.
// ---------------------------------------------------------------------------

typedef __bf16 bf16;
typedef float  f32x4  __attribute__((ext_vector_type(4)));
typedef __bf16 bf16x8 __attribute__((ext_vector_type(8)));
typedef __bf16 bf16x4v __attribute__((ext_vector_type(4)));

#define DEVI __device__ __forceinline__

DEVI void gload16(const bf16* g, bf16* l) {
  __builtin_amdgcn_global_load_lds(
      (const __attribute__((address_space(1))) void*)g,
      (__attribute__((address_space(3))) void*)l, 16, 0, 0);
}

struct GemmArgs {
  const bf16* A; const bf16* B;
  bf16* Cn;   // normal write:  [z] row-major [m][col], nullable
  bf16* Ct;   // transposed:    [z] row-major [col][m], nullable
  int lda, ldb, ldcn, ldct, K, zshB, zshC;
  long sB, sCn, sCt;   // per-z element strides
};

struct TaskDesc { GemmArgs g; int kind, gx, blk0, nblk; };
struct MultiArgs { TaskDesc t[3]; int nt; };

// 2-phase double-buffered NT GEMM, BK=64. 4 waves (2x2), 16x16x32 bf16 MFMA.
template<int BM, int BN>
DEVI void gemm_body(const GemmArgs& g, int bx, int by, bf16* smem) {
  constexpr int BK  = 64;
  constexpr int ASZ = BM * BK, BSZ = BN * BK;
  bf16* Abuf = smem;
  bf16* Bbuf = smem + 2 * ASZ;
  const int tid  = threadIdx.x;
  const int wave = tid >> 6;
  const int lane = tid & 63;
  const int wm = (wave >> 1) * (BM / 2);
  const int wn = (wave & 1) * (BN / 2);
  constexpr int FM = BM / 32;
  constexpr int FN = BN / 32;

  const int sseg = (((tid & 7) ^ ((tid >> 3) & 7))) * 8;  // swz source seg
  const int l15  = lane & 15;
  const int lq   = lane >> 4;

  const bf16* arow[BM / 32];
  #pragma unroll
  for (int c = 0; c < BM / 32; ++c)
    arow[c] = g.A + (long)(bx * BM + c * 32 + (tid >> 3)) * g.lda + sseg;
  const bf16* brow[BN / 32];
  const int maskB = (1 << g.zshB) - 1;
  #pragma unroll
  for (int c = 0; c < BN / 32; ++c) {
    const int nb = by * BN + c * 32 + (tid >> 3);
    brow[c] = g.B + (long)(nb >> g.zshB) * g.sB + (long)(nb & maskB) * g.ldb + sseg;
  }

  f32x4 acc[FM][FN] = {};

  auto stage = [&](int buf, int kt) {
    #pragma unroll
    for (int c = 0; c < BM / 32; ++c)
      gload16(arow[c] + kt, &Abuf[buf * ASZ + c * 2048 + tid * 8]);
    #pragma unroll
    for (int c = 0; c < BN / 32; ++c)
      gload16(brow[c] + kt, &Bbuf[buf * BSZ + c * 2048 + tid * 8]);
  };
  auto compute = [&](int cb) {
    #pragma unroll
    for (int kk = 0; kk < 2; ++kk) {
      bf16x8 af[FM], bfr[FN];
      #pragma unroll
      for (int i = 0; i < FM; ++i) {
        const int R = wm + i * 16 + l15;
        af[i] = *(const bf16x8*)
            &Abuf[cb * ASZ + R * 64 + ((kk * 4 + lq) ^ (l15 & 7)) * 8];
      }
      #pragma unroll
      for (int j = 0; j < FN; ++j) {
        const int R = wn + j * 16 + l15;
        bfr[j] = *(const bf16x8*)
            &Bbuf[cb * BSZ + R * 64 + ((kk * 4 + lq) ^ (l15 & 7)) * 8];
      }
      #pragma unroll
      for (int i = 0; i < FM; ++i)
        #pragma unroll
        for (int j = 0; j < FN; ++j)
          acc[i][j] = __builtin_amdgcn_mfma_f32_16x16x32_bf16(af[i], bfr[j],
                                                              acc[i][j], 0, 0, 0);
    }
  };

  const int nt = g.K / BK;
  stage(0, 0);
  __syncthreads();
  int cur = 0;
  for (int t = 0; t < nt; ++t) {
    if (t + 1 < nt) stage(cur ^ 1, (t + 1) * BK);
    compute(cur);
    __syncthreads();
    cur ^= 1;
  }

  const int gm0 = bx * BM + wm;
  const int gn0 = by * BN + wn;
  const int rowq = lq * 4;
  const int maskC = (1 << g.zshC) - 1;
  if (g.Cn) {
    #pragma unroll
    for (int i = 0; i < FM; ++i)
      #pragma unroll
      for (int j = 0; j < FN; ++j) {
        const int m0 = gm0 + i * 16 + rowq;
        const int ng = gn0 + j * 16 + l15;
        bf16* Cz = g.Cn + (long)(ng >> g.zshC) * g.sCn + (ng & maskC);
        #pragma unroll
        for (int r = 0; r < 4; ++r)
          Cz[(long)(m0 + r) * g.ldcn] = (bf16)acc[i][j][r];
      }
  }
  if (g.Ct) {
    #pragma unroll
    for (int i = 0; i < FM; ++i)
      #pragma unroll
      for (int j = 0; j < FN; ++j) {
        const int m0 = gm0 + i * 16 + rowq;
        const int ng = gn0 + j * 16 + l15;
        bf16x4v v = { (bf16)acc[i][j][0], (bf16)acc[i][j][1],
                      (bf16)acc[i][j][2], (bf16)acc[i][j][3] };
        *(bf16x4v*)(g.Ct + (long)(ng >> g.zshC) * g.sCt
                    + (long)(ng & maskC) * g.ldct + m0) = v;
      }
  }
}

template<int SME>
__global__ __launch_bounds__(256) void gemm_multi_t(MultiArgs mu) {
  __shared__ bf16 smem[SME];
  const int b = blockIdx.x;
  int ti = 0;
  if (mu.nt > 1 && b >= mu.t[1].blk0) ti = 1;
  if (mu.nt > 2 && b >= mu.t[2].blk0) ti = 2;
  const TaskDesc t = mu.t[ti];
  const int local = b - t.blk0;
  int bx, by;
  if ((t.gx & 7) == 0) {
    const int xcd = local & 7;
    const int idx = local >> 3;
    const int sub = t.gx >> 3;
    bx = xcd * sub + idx % sub;
    by = idx / sub;
  } else {
    bx = local % t.gx;
    by = local / t.gx;
  }
  if (t.kind == 0) {
    if (SME >= 32768) gemm_body<128, 128>(t.g, bx, by, smem);
  } else if (t.kind == 1) {
    if (SME >= 24576) gemm_body< 64, 128>(t.g, bx, by, smem);
  } else if (t.kind == 2) {
    if (SME >= 24576) gemm_body<128,  64>(t.g, bx, by, smem);
  } else {
    gemm_body< 64,  64>(t.g, bx, by, smem);
  }
}

// ---------------- prep / elementwise kernels -------------------------------

struct PrepA {
  const float* src[6]; bf16* dst[6]; int fin[6], fout[6], sh[6], b0[7];
  const float* Wb1;  const float* E0_1; const float* E1_1;
  const float* Wbg2; const float* E0g2; const float* E1g2;
  bf16* We1T1; bf16* We1T2; float* T1f; float* T2f;
  const float* aw1; const float* al1; float* s1;
  const float* aw2; const float* al2; float* s2;
};

// prep_all1 ranges:
//   [0,2048)      S0 pad (1 block/row)
//   [2048,6144)   M pad (2 blocks/row)
//   [6144,10240)  S1 transpose tiles -> writes BOTH S1Tb and S1b
//   [10240,10833) prep_a weight work
//   [10833,12881) tem1 build
struct Prep1Args {
  const float* S0; const float* S1; const float* M;
  bf16* S0b; bf16* S1b; bf16* Mb; bf16* S1Tb;
  const float* x; const float* h; bf16* tem;
  PrepA pa;
};
__global__ __launch_bounds__(256) void prep_all1(Prep1Args g) {
  __shared__ float tt[64][65];
  const int b = blockIdx.x, t = threadIdx.x;
  if (b < 2048) {
    // S0 pad: row b, cols t*8..t*8+7
    const int r = b;
    const int c0 = t * 8;
    bf16x8 v;
    if (r < 2000 && c0 + 7 < 2000) {
      const float4 a = *(const float4*)&g.S0[(long)r * 2000 + c0];
      const float4 bb = *(const float4*)&g.S0[(long)r * 2000 + c0 + 4];
      v[0]=(bf16)a.x; v[1]=(bf16)a.y; v[2]=(bf16)a.z; v[3]=(bf16)a.w;
      v[4]=(bf16)bb.x; v[5]=(bf16)bb.y; v[6]=(bf16)bb.z; v[7]=(bf16)bb.w;
    } else {
      #pragma unroll
      for (int k = 0; k < 8; ++k) {
        const int c = c0 + k;
        v[k] = (bf16)((r < 2000 && c < 2000) ? g.S0[(long)r * 2000 + c] : 0.f);
      }
    }
    *(bf16x8*)&g.S0b[(long)r * 2048 + c0] = v;
  } else if (b < 6144) {
    // M pad: 2 blocks/row
    const int y = b - 2048;
    const int r = y >> 1;
    const int c0 = ((y & 1) * 256 + t) * 8;
    bf16x8 v;
    if (r < 2000 && c0 + 7 < 4000) {
      const float4 a = *(const float4*)&g.M[(long)r * 4000 + c0];
      const float4 bb = *(const float4*)&g.M[(long)r * 4000 + c0 + 4];
      v[0]=(bf16)a.x; v[1]=(bf16)a.y; v[2]=(bf16)a.z; v[3]=(bf16)a.w;
      v[4]=(bf16)bb.x; v[5]=(bf16)bb.y; v[6]=(bf16)bb.z; v[7]=(bf16)bb.w;
    } else {
      #pragma unroll
      for (int k = 0; k < 8; ++k) {
        const int c = c0 + k;
        v[k] = (bf16)((r < 2000 && c < 4000) ? g.M[(long)r * 4000 + c] : 0.f);
      }
    }
    *(bf16x8*)&g.Mb[(long)r * 4096 + c0] = v;
  } else if (b < 10240) {
    // S1: one 64x64 tile -> straight pad (S1b) + transpose pad (S1Tb)
    const int tb = b - 6144;
    const int r0 = (tb & 63) * 64;
    const int c0 = (tb >> 6) * 64;
    const int row = t >> 2;
    const int seg = (t & 3) * 16;
    const int r = r0 + row;
    bf16 sv[16];
    #pragma unroll
    for (int q = 0; q < 4; ++q) {
      const int c = c0 + seg + q * 4;
      float4 a;
      if (r < 4000 && c + 3 < 4000) a = *(const float4*)&g.S1[(long)r * 4000 + c];
      else {
        a.x = (r < 4000 && c     < 4000) ? g.S1[(long)r * 4000 + c    ] : 0.f;
        a.y = (r < 4000 && c + 1 < 4000) ? g.S1[(long)r * 4000 + c + 1] : 0.f;
        a.z = (r < 4000 && c + 2 < 4000) ? g.S1[(long)r * 4000 + c + 2] : 0.f;
        a.w = (r < 4000 && c + 3 < 4000) ? g.S1[(long)r * 4000 + c + 3] : 0.f;
      }
      tt[seg + q * 4 + 0][row] = a.x;
      tt[seg + q * 4 + 1][row] = a.y;
      tt[seg + q * 4 + 2][row] = a.z;
      tt[seg + q * 4 + 3][row] = a.w;
      sv[q * 4 + 0] = (bf16)a.x;
      sv[q * 4 + 1] = (bf16)a.y;
      sv[q * 4 + 2] = (bf16)a.z;
      sv[q * 4 + 3] = (bf16)a.w;
    }
    // straight-padded write (independent of LDS)
    {
      bf16x8 w0, w1;
      #pragma unroll
      for (int k = 0; k < 8; ++k) { w0[k] = sv[k]; w1[k] = sv[8 + k]; }
      *(bf16x8*)&g.S1b[(long)r * 4096 + c0 + seg] = w0;
      *(bf16x8*)&g.S1b[(long)r * 4096 + c0 + seg + 8] = w1;
    }
    __syncthreads();
    const int orow = t >> 2;
    const int oseg = (t & 3) * 16;
    bf16x8 v0, v1;
    #pragma unroll
    for (int k = 0; k < 8; ++k) {
      v0[k] = (bf16)tt[orow][oseg + k];
      v1[k] = (bf16)tt[orow][oseg + 8 + k];
    }
    *(bf16x8*)&g.S1Tb[(long)(c0 + orow) * 4096 + r0 + oseg] = v0;
    *(bf16x8*)&g.S1Tb[(long)(c0 + orow) * 4096 + r0 + oseg + 8] = v1;
  } else if (b < 10833) {
    const PrepA& a = g.pa;
    const int pb = b - 10240;
    if (pb < 416) {
      int k = 0;
      while (pb >= a.b0[k + 1]) ++k;
      const int i = (pb - a.b0[k]) * 256 + t;
      const int c = i >> a.sh[k], f = i & ((1 << a.sh[k]) - 1);
      float v = (f < a.fin[k]) ? a.src[k][(long)f * a.fout[k] + c] : 0.f;
      a.dst[k][i] = (bf16)v;
    } else if (pb < 480) {
      const int i = (pb - 416) * 256 + t;
      const int c = i >> 7, f = i & 127;
      float s = 0.f;
      if (f < 66) {
        #pragma unroll 16
        for (int k = 0; k < 128; ++k) s += a.E0_1[k * 128 + c] * a.Wb1[f * 128 + k];
      }
      a.We1T1[c * 128 + f] = (bf16)s;
    } else if (pb < 512) {
      const int i = (pb - 480) * 256 + t;
      const int c = i >> 7, f = i & 127;
      float s = 0.f;
      if (f < 66) {
        #pragma unroll 16
        for (int k = 0; k < 64; ++k) s += a.E0g2[k * 64 + c] * a.Wbg2[f * 64 + k];
      }
      a.We1T2[c * 128 + f] = (bf16)s;
    } else if (pb < 576) {
      const int i = (pb - 512) * 256 + t;
      const int j = i >> 7, c = i & 127;
      float s = 0.f;
      #pragma unroll 16
      for (int k = 0; k < 128; ++k) s += a.E0_1[j * 128 + k] * a.E1_1[k * 128 + c];
      a.T1f[j * 128 + c] = s;
    } else if (pb < 592) {
      const int i = (pb - 576) * 256 + t;
      const int j = i >> 6, c = i & 63;
      float s = 0.f;
      #pragma unroll 16
      for (int k = 0; k < 64; ++k) s += a.E0g2[j * 64 + k] * a.E1g2[k * 64 + c];
      a.T2f[j * 64 + c] = s;
    } else {
      if (t < 128) {
        float s = 0.f;
        for (int w = 0; w < 128; ++w) s += a.aw1[w * 128 + t] * a.al1[w];
        a.s1[t] = s;
      } else if (t < 192) {
        const int f = t - 128;
        float s = 0.f;
        for (int w = 0; w < 64; ++w) s += a.aw2[w * 64 + f] * a.al2[w];
        a.s2[f] = s;
      }
    }
  } else {
    const long base = (long)(b - 10833) * 2048 + t * 8;
    const int gn = (int)(base >> 7);
    const int f0 = (int)(base & 127);
    const int z = gn >> 11, n = gn & 2047;
    bf16x8 v;
    #pragma unroll
    for (int k = 0; k < 8; ++k) {
      const int f = f0 + k;
      float val = 0.f;
      if (n < 2000) {
        if (f < 2)       val = g.x[(long)z * 4000 + n * 2 + f];
        else if (f < 66) val = g.h[(long)z * 128000 + (long)n * 64 + (f - 2)];
      }
      v[k] = (bf16)val;
    }
    *(bf16x8*)&g.tem[base] = v;
  }
}

// prep_all2: We2^T = Wb*T (96 blocks).
struct Prep2Args {
  const float* Wb1; const float* Wbg2;
  const float* T1f; const float* T2f;
  bf16* We2T1; bf16* We2T2;
};
__global__ __launch_bounds__(256) void prep_all2(Prep2Args a) {
  const int b = blockIdx.x, t = threadIdx.x;
  if (b < 64) {
    const int i = b * 256 + t;
    const int c = i >> 7, f = i & 127;
    float s = 0.f;
    if (f < 66) {
      #pragma unroll 16
      for (int j = 0; j < 128; ++j) s += a.Wb1[f * 128 + j] * a.T1f[j * 128 + c];
    }
    a.We2T1[c * 128 + f] = (bf16)s;
  } else {
    const int i = (b - 64) * 256 + t;
    const int c = i >> 7, f = i & 127;
    float s = 0.f;
    if (f < 66) {
      #pragma unroll 16
      for (int j = 0; j < 64; ++j) s += a.Wbg2[f * 64 + j] * a.T2f[j * 64 + c];
    }
    a.We2T2[c * 128 + f] = (bf16)s;
  }
}

// g1 attention (F=128) fused with build_tem2.
__global__ void attention_fuse(const bf16* hop0, const bf16* hop1,
                               const bf16* hop2, const float* s,
                               const float* x, const float* h,
                               bf16* fea64, bf16* tem) {
  const int nloc = blockIdx.x * 4 + (threadIdx.x >> 6);
  const int b = blockIdx.y;
  const int lane = threadIdx.x & 63;
  const long bn = (long)b * 2048 + nloc;
  float h0[2], h1[2], h2[2];
  float d0 = 0.f, d1 = 0.f, d2 = 0.f;
  #pragma unroll
  for (int q = 0; q < 2; ++q) {
    const int f = lane + q * 64;
    h0[q] = (float)hop0[bn * 256 + f];
    h1[q] = (float)hop1[bn * 256 + f];
    h2[q] = (float)hop2[bn * 128 + f];
    const float sv = s[f];
    d0 += h0[q] * sv; d1 += h1[q] * sv; d2 += h2[q] * sv;
  }
  #pragma unroll
  for (int o = 32; o; o >>= 1) {
    d0 += __shfl_xor(d0, o); d1 += __shfl_xor(d1, o); d2 += __shfl_xor(d2, o);
  }
  const float mx = fmaxf(d0, fmaxf(d1, d2));
  float e0 = expf(d0 - mx), e1 = expf(d1 - mx), e2 = expf(d2 - mx);
  const float inv = 1.f / (e0 + e1 + e2);
  e0 *= inv; e1 *= inv; e2 *= inv;
  const float o0 = e0 * h0[0] + e1 * h1[0] + e2 * h2[0];
  const float o1 = e0 * h0[1] + e1 * h1[1] + e2 * h2[1];   // r-gate
  fea64[bn * 64 + lane] = (bf16)o0;
  const float r0 = __shfl(o1, (lane >= 2) ? lane - 2 : 0);
  const float r1 = __shfl(o1, (62 + lane) & 63);
  float t0 = 0.f, t1 = 0.f;
  if (nloc < 2000) {
    const long hb = (long)b * 128000 + (long)nloc * 64;
    if (lane < 2) {
      t0 = x[(long)b * 4000 + nloc * 2 + lane];
      t1 = (1.f / (1.f + expf(-r1))) * h[hb + 62 + lane];
    } else {
      t0 = (1.f / (1.f + expf(-r0))) * h[hb + (lane - 2)];
    }
  }
  tem[bn * 128 + lane] = (bf16)t0;
  tem[bn * 128 + 64 + lane] = (bf16)t1;
}

// g2 attention (F=64) fused with gru_out.
__global__ void attention_gru(const bf16* hop0, const bf16* hop1,
                              const bf16* hop2, const float* s,
                              const bf16* fea64, const float* h, float* out) {
  const int nloc = blockIdx.x * 4 + (threadIdx.x >> 6);
  const int b = blockIdx.y;
  const int lane = threadIdx.x & 63;
  const long bn = (long)b * 2048 + nloc;
  const float a0 = (float)hop0[bn * 128 + lane];
  const float a1 = (float)hop1[bn * 128 + lane];
  const float a2 = (float)hop2[bn * 64 + lane];
  const float sv = s[lane];
  float d0 = a0 * sv, d1 = a1 * sv, d2 = a2 * sv;
  #pragma unroll
  for (int o = 32; o; o >>= 1) {
    d0 += __shfl_xor(d0, o); d1 += __shfl_xor(d1, o); d2 += __shfl_xor(d2, o);
  }
  const float mx = fmaxf(d0, fmaxf(d1, d2));
  float e0 = expf(d0 - mx), e1 = expf(d1 - mx), e2 = expf(d2 - mx);
  const float inv = 1.f / (e0 + e1 + e2);
  e0 *= inv; e1 *= inv; e2 *= inv;
  const float c = e0 * a0 + e1 * a1 + e2 * a2;
  if (nloc < 2000) {
    const float z  = (float)fea64[bn * 64 + lane];
    const float hv = h[(long)b * 128000 + (long)nloc * 64 + lane];
    const float zs = 1.f / (1.f + expf(-z));
    out[(long)b * 128000 + (long)nloc * 64 + lane] =
        zs * hv + (1.f - zs) * tanhf(c);
  }
}

__global__ void ws_diag(float* out, int n, float v) {
  int i = blockIdx.x * blockDim.x + threadIdx.x;
  if (i < n) out[i] = v;
}

// ---------------------------------------------------------------------------

static TaskDesc TD(int kind, int gx, int nblk,
                   const bf16* A, int lda,
                   const bf16* B, int ldb, int zshB, long sB,
                   bf16* Cn, int ldcn, long sCn,
                   bf16* Ct, int ldct, long sCt, int zshC, int K) {
  TaskDesc t;
  t.g = GemmArgs{A, B, Cn, Ct, lda, ldb, ldcn, ldct, K, zshB, zshC, sB, sCn, sCt};
  t.kind = kind; t.gx = gx; t.blk0 = 0; t.nblk = nblk;
  return t;
}
static void runT(hipStream_t st, int n, const TaskDesc* ts) {
  MultiArgs m = {};
  int off = 0, req = 0;
  static const int kreq[4] = {32768, 24576, 24576, 16384};
  for (int i = 0; i < n; ++i) {
    m.t[i] = ts[i]; m.t[i].blk0 = off; off += ts[i].nblk;
    if (kreq[ts[i].kind] > req) req = kreq[ts[i].kind];
  }
  m.nt = n;
  if (req <= 16384)      gemm_multi_t<16384><<<off, 256, 0, st>>>(m);  // 32 KB
  else if (req <= 24576) gemm_multi_t<24576><<<off, 256, 0, st>>>(m);  // 48 KB
  else                   gemm_multi_t<32768><<<off, 256, 0, st>>>(m);  // 64 KB
}
static void run1(hipStream_t st, TaskDesc a) { runT(st, 1, &a); }
static void run2p(hipStream_t st, TaskDesc a, TaskDesc b) {
  TaskDesc ts[2] = {a, b}; runT(st, 2, ts);
}
static void run3p(hipStream_t st, TaskDesc a, TaskDesc b, TaskDesc c) {
  TaskDesc ts[3] = {a, b, c}; runT(st, 3, ts);
}

extern "C" void kernel_launch(void* const* d_in, const int* in_sizes, int n_in,
                              void* d_out, int out_size, void* d_ws, size_t ws_size,
                              hipStream_t stream) {
  const float* x    = (const float*)d_in[0];
  const float* hid  = (const float*)d_in[1];
  const float* S0   = (const float*)d_in[2];
  const float* S1   = (const float*)d_in[3];
  const float* M    = (const float*)d_in[4];

  char* base = (char*)d_ws;
  size_t off = 0;
  auto alloc = [&](size_t bytes) -> void* {
    void* r = base + off;
    off += (bytes + 255) & ~(size_t)255;
    return r;
  };

  bf16* S0b  = (bf16*)alloc(2048ull * 2048 * 2);   //  8 MB
  bf16* S1b  = (bf16*)alloc(4096ull * 4096 * 2);   // 32 MB
  bf16* S1Tb = (bf16*)alloc(4096ull * 4096 * 2);   // 32 MB
  bf16* Mb   = (bf16*)alloc(2048ull * 4096 * 2);   // 16 MB
  bf16* tem  = (bf16*)alloc(16ull * 2048 * 128 * 2);  // 8 MB

  bf16* WtAll1 = (bf16*)alloc(384 * 128 * 2);
  bf16* W1T    = (bf16*)alloc(128 * 256 * 2);
  bf16* W2T    = (bf16*)alloc(128 * 256 * 2);
  bf16* WtAll2 = (bf16*)alloc(192 * 128 * 2);
  bf16* W1g2T  = (bf16*)alloc(64 * 128 * 2);
  bf16* W2g2T  = (bf16*)alloc(64 * 128 * 2);
  float* s1  = (float*)alloc(128 * 4);
  float* s2  = (float*)alloc(64 * 4);
  float* T1f = (float*)alloc(128 * 128 * 4);
  float* T2f = (float*)alloc(64 * 64 * 4);

  bf16* P1 = (bf16*)alloc(2048ull * 2048 * 2);     //  8 MB
  bf16* P2 = (bf16*)alloc(2048ull * 2048 * 2);     //  8 MB
  bf16* R  = (bf16*)alloc(2048ull * 4096 * 2);     // 16 MB
  bf16* R2 = (bf16*)alloc(2048ull * 4096 * 2);     // 16 MB

  if (off > ws_size) {
    ws_diag<<<4, 256, 0, stream>>>((float*)d_out, 1024, (float)(ws_size >> 20));
    return;
  }

  // Overlays (liveness-audited, identical to r8..r16):
  bf16* xAll   = S1b;
  bf16* cat1   = S1Tb;
  bf16* cat2   = (bf16*)((char*)S1Tb + 16777216);
  bf16* cpb    = S1b;
  bf16* hop2   = (bf16*)((char*)S1b + 8388608);
  bf16* fea64  = (bf16*)((char*)S1b + 16777216);
  bf16* xAll2  = R;
  bf16* cat1_2 = S1Tb;
  bf16* cat2_2 = (bf16*)((char*)S1Tb + 8388608);
  bf16* cpb2   = S1b;
  bf16* hop2_2 = (bf16*)((char*)S1b + 8388608);

  // ---- prep (2 launches) ----
  Prep1Args p1;
  p1.S0 = S0; p1.S1 = S1; p1.M = M;
  p1.S0b = S0b; p1.S1b = S1b; p1.Mb = Mb; p1.S1Tb = S1Tb;
  p1.x = x; p1.h = hid; p1.tem = tem;
  {
    PrepA& pa = p1.pa;
    const float* wsrc[6] = {(const float*)d_in[6], (const float*)d_in[7],
                            (const float*)d_in[8], (const float*)d_in[14],
                            (const float*)d_in[15], (const float*)d_in[16]};
    bf16* wdst[6] = {WtAll1, W1T, W2T, WtAll2, W1g2T, W2g2T};
    static const int wfin[6]  = {66, 256, 256, 66, 128, 128};
    static const int wfout[6] = {128, 128, 128, 64, 64, 64};
    static const int wsh[6]   = {7, 8, 8, 7, 7, 7};
    static const int wb0[7]   = {0, 64, 192, 320, 352, 384, 416};
    for (int i = 0; i < 6; ++i) {
      pa.src[i] = wsrc[i]; pa.dst[i] = wdst[i];
      pa.fin[i] = wfin[i]; pa.fout[i] = wfout[i]; pa.sh[i] = wsh[i];
    }
    for (int i = 0; i < 7; ++i) pa.b0[i] = wb0[i];
    pa.Wb1  = (const float*)d_in[5];  pa.E0_1 = (const float*)d_in[9];
    pa.E1_1 = (const float*)d_in[10];
    pa.Wbg2 = (const float*)d_in[13]; pa.E0g2 = (const float*)d_in[17];
    pa.E1g2 = (const float*)d_in[18];
    pa.We1T1 = WtAll1 + 128 * 128;  pa.We1T2 = WtAll2 + 64 * 128;
    pa.T1f = T1f; pa.T2f = T2f;
    pa.aw1 = (const float*)d_in[11]; pa.al1 = (const float*)d_in[12]; pa.s1 = s1;
    pa.aw2 = (const float*)d_in[19]; pa.al2 = (const float*)d_in[20]; pa.s2 = s2;
  }
  prep_all1<<<12881, 256, 0, stream>>>(p1);
  Prep2Args p2{(const float*)d_in[5], (const float*)d_in[13], T1f, T2f,
               WtAll1 + 256 * 128, WtAll2 + 128 * 128};
  prep_all2<<<96, 256, 0, stream>>>(p2);

  // ---- L1: R = M*S1, R2 = M*S1^T ----
  run2p(stream,
    TD(0, 16, 512, Mb,4096, S1Tb,4096,12,0, R,4096,0,  nullptr,0,0, 12, 4096),
    TD(0, 16, 512, Mb,4096, S1b,4096,12,0,  R2,4096,0, nullptr,0,0, 12, 4096));
  // ---- L2: P1 = R*M^T, P2 = R*R2^T, xAll proj (co-resident 2/CU) ----
  run3p(stream,
    TD(0, 16, 256, R,4096, Mb,4096,11,0, P1,2048,0, nullptr,0,0, 11, 4096),
    TD(0, 16, 256, R,4096, R2,4096,11,0, P2,2048,0, nullptr,0,0, 11, 4096),
    TD(0, 3, 768, WtAll1,128, tem,128,11,2048L*128,
       xAll,2048,384L*2048, nullptr,0,0, 11, 128));
  // ---- L3: cat1 = [S0*xW0 | P1*xe1], cat2_hi = P2*xe2 ----
  run3p(stream,
    TD(0, 16, 256, S0b,2048, xAll,2048,7,384L*2048,
       cat1,256,2048L*256, nullptr,0,0, 7, 2048),
    TD(0, 16, 256, P1,2048, xAll+128*2048,2048,7,384L*2048,
       cat1+128,256,2048L*256, nullptr,0,0, 7, 2048),
    TD(0, 16, 256, P2,2048, xAll+256*2048,2048,7,384L*2048,
       cat2+128,256,2048L*256, nullptr,0,0, 7, 2048));
  // ---- L4-L7: serial g1 tail (512-block) ----
  run1(stream, TD(2, 1, 512, W1T,256, cat1,256,11,2048L*256,
                  cpb,2048,128L*2048, nullptr,0,0, 11, 256));
  run1(stream, TD(2, 16, 512, S0b,2048, cpb,2048,7,128L*2048,
                  cat2,256,2048L*256, nullptr,0,0, 7, 2048));
  run1(stream, TD(2, 1, 512, W2T,256, cat2,256,11,2048L*256,
                  cpb,2048,128L*2048, nullptr,0,0, 11, 256));
  run1(stream, TD(2, 16, 512, S0b,2048, cpb,2048,7,128L*2048,
                  hop2,128,2048L*128, nullptr,0,0, 7, 2048));
  attention_fuse<<<dim3(512, 16), 256, 0, stream>>>(cat1, cat2, hop2, s1,
                                                    x, hid, fea64, tem);

  // ---- L8: g2 projection (768 blocks; 48 KB -> all co-resident) ----
  run1(stream, TD(1, 3, 768, WtAll2,128, tem,128,11,2048L*128,
                  xAll2,2048,192L*2048, nullptr,0,0, 11, 128));
  // ---- L9: g2 leading aggs (768 blocks; 48 KB -> all co-resident) ----
  run3p(stream,
    TD(2, 16, 256, S0b,2048, xAll2,2048,6,192L*2048,
       cat1_2,128,2048L*128, nullptr,0,0, 6, 2048),
    TD(2, 16, 256, P1,2048, xAll2+64*2048,2048,6,192L*2048,
       cat1_2+64,128,2048L*128, nullptr,0,0, 6, 2048),
    TD(2, 16, 256, P2,2048, xAll2+128*2048,2048,6,192L*2048,
       cat2_2+64,128,2048L*128, nullptr,0,0, 6, 2048));
  // ---- L10-L13: serial g2 tail (kind3, 32 KB LDS) ----
  run1(stream, TD(3, 1, 512, W1g2T,128, cat1_2,128,11,2048L*128,
                  cpb2,2048,64L*2048, nullptr,0,0, 11, 128));
  run1(stream, TD(3, 32, 512, S0b,2048, cpb2,2048,6,64L*2048,
                  cat2_2,128,2048L*128, nullptr,0,0, 6, 2048));
  run1(stream, TD(3, 1, 512, W2g2T,128, cat2_2,128,11,2048L*128,
                  cpb2,2048,64L*2048, nullptr,0,0, 11, 128));
  run1(stream, TD(3, 32, 512, S0b,2048, cpb2,2048,6,64L*2048,
                  hop2_2,64,2048L*64, nullptr,0,0, 6, 2048));
  attention_gru<<<dim3(512, 16), 256, 0, stream>>>(cat1_2, cat2_2, hop2_2, s2,
                                                   fea64, hid, (float*)d_out);
}